// Round 1
// baseline (902.480 us; speedup 1.0000x reference)
//
#include <hip/hip_runtime.h>
#include <hip/hip_bf16.h>

typedef __attribute__((ext_vector_type(8))) __bf16 bf16x8;
typedef __attribute__((ext_vector_type(4))) float floatx4;

#define NVALID 3000
#define NPAD   3072
#define FEA    128

// ---------------------------------------------------------------- MLP layer
// Y[m,o] = relu( sum_i X[m,i]*W[o,i] + b[o] ), F=128. 8 rows per block.
__global__ __launch_bounds__(256) void mlp_layer(
    const float* __restrict__ X, const float* __restrict__ W,
    const float* __restrict__ b, float* __restrict__ Y, int M)
{
    __shared__ float Xs[8][128];
    const int t = threadIdx.x;
    const int m0 = blockIdx.x * 8;
    for (int s2 = t; s2 < 1024; s2 += 256) {
        int r = s2 >> 7, ii = s2 & 127;
        int mm = m0 + r;
        Xs[r][ii] = (mm < M) ? X[(size_t)mm * 128 + ii] : 0.f;
    }
    __syncthreads();
    const int o = t & 127, rh = t >> 7;
    float a0 = 0.f, a1 = 0.f, a2 = 0.f, a3 = 0.f;
    const float* wrow = W + (size_t)o * 128;
    for (int i = 0; i < 128; ++i) {
        float w = wrow[i];
        a0 += Xs[rh + 0][i] * w;
        a1 += Xs[rh + 2][i] * w;
        a2 += Xs[rh + 4][i] * w;
        a3 += Xs[rh + 6][i] * w;
    }
    const float bo = b[o];
    int mm;
    mm = m0 + rh + 0; if (mm < M) Y[(size_t)mm * 128 + o] = fmaxf(a0 + bo, 0.f);
    mm = m0 + rh + 2; if (mm < M) Y[(size_t)mm * 128 + o] = fmaxf(a1 + bo, 0.f);
    mm = m0 + rh + 4; if (mm < M) Y[(size_t)mm * 128 + o] = fmaxf(a2 + bo, 0.f);
    mm = m0 + rh + 6; if (mm < M) Y[(size_t)mm * 128 + o] = fmaxf(a3 + bo, 0.f);
}

// ---------------------------------------------------------------- gtconv
__device__ __forceinline__ void softmax5(const float* __restrict__ w, float* s)
{
    float m = w[0];
    #pragma unroll
    for (int e = 1; e < 5; ++e) m = fmaxf(m, w[e]);
    float sum = 0.f;
    #pragma unroll
    for (int e = 0; e < 5; ++e) { s[e] = __expf(w[e] - m); sum += s[e]; }
    float r = 1.f / sum;
    #pragma unroll
    for (int e = 0; e < 5; ++e) s[e] *= r;
}

// One channel: a0 (row-major), b0^T, g1^T  all (NPAD x NPAD) bf16, zero padded.
__global__ __launch_bounds__(256) void gtconv_chan(
    const float* __restrict__ A, const float* __restrict__ w0a,
    const float* __restrict__ w0b, const float* __restrict__ w1, int c,
    __hip_bfloat16* __restrict__ a0, __hip_bfloat16* __restrict__ bT,
    __hip_bfloat16* __restrict__ gT)
{
    float sa[5], sb[5], sg[5];
    softmax5(w0a + c * 5, sa);
    softmax5(w0b + c * 5, sb);
    softmax5(w1 + c * 5, sg);

    __shared__ float At[5][32][33];
    const int bi = blockIdx.y * 32, bj = blockIdx.x * 32;
    const int t = threadIdx.x, tr = t >> 5, tc = t & 31;

    for (int e = 0; e < 5; ++e) {
        #pragma unroll
        for (int p = 0; p < 4; ++p) {
            int i = tr + p * 8;
            int gi = bi + i, gj = bj + tc;
            At[e][i][tc] = (gi < NVALID && gj < NVALID)
                         ? A[(size_t)e * 9000000 + (size_t)gi * 3000 + gj] : 0.f;
        }
    }
    __syncthreads();
    #pragma unroll
    for (int p = 0; p < 4; ++p) {
        int i = tr + p * 8;
        float va = 0.f;
        #pragma unroll
        for (int e = 0; e < 5; ++e) va += sa[e] * At[e][i][tc];
        a0[(size_t)(bi + i) * NPAD + bj + tc] = __float2bfloat16(va);
    }
    #pragma unroll
    for (int p = 0; p < 4; ++p) {
        int jj = tr + p * 8;
        float vb = 0.f, vg = 0.f;
        #pragma unroll
        for (int e = 0; e < 5; ++e) {
            float x = At[e][tc][jj];
            vb += sb[e] * x; vg += sg[e] * x;
        }
        bT[(size_t)(bj + jj) * NPAD + bi + tc] = __float2bfloat16(vb);
        gT[(size_t)(bj + jj) * NPAD + bi + tc] = __float2bfloat16(vg);
    }
}

// ---------------------------------------------------------------- row degree
// MODE 0: rownorm  -> out = 1/(rowsum+1)
// MODE 1: sgc      -> out = rsqrt(rowsum+2)
template<int MODE>
__global__ __launch_bounds__(256) void rowdeg(
    const float* __restrict__ src, int ld, int nvalid, float* __restrict__ outv)
{
    const int i = blockIdx.x, t = threadIdx.x;
    float s = 0.f;
    if (i < nvalid)
        for (int j = t; j < nvalid; j += 256) s += src[(size_t)i * ld + j];
    #pragma unroll
    for (int off = 32; off > 0; off >>= 1) s += __shfl_down(s, off);
    __shared__ float red[4];
    if ((t & 63) == 0) red[t >> 6] = s;
    __syncthreads();
    if (t == 0) {
        float tot = red[0] + red[1] + red[2] + red[3];
        outv[i] = (MODE == 0) ? 1.f / (tot + 1.f) : rsqrtf(tot + 2.f);
    }
}

// MODE 0: dst = (src + I) * vec[i]          (row-normalize)
// MODE 1: dst = (src + 2I) * vec[i]*vec[j]  (sym sgc normalize)
template<int MODE>
__global__ __launch_bounds__(256) void scale_cast(
    const float* __restrict__ src, int lds_, int nvalid,
    const float* __restrict__ vec, __hip_bfloat16* __restrict__ dst)
{
    const int i = blockIdx.y;
    const int j0 = (blockIdx.x * 256 + threadIdx.x) * 4;
    const float vi = vec[i];
    #pragma unroll
    for (int u = 0; u < 4; ++u) {
        int j = j0 + u;
        float v = (i < nvalid && j < nvalid) ? src[(size_t)i * lds_ + j] : 0.f;
        if (j == i) v += (MODE == 0) ? 1.f : 2.f;
        float o = (MODE == 0) ? v * vi : v * vi * vec[j];
        dst[(size_t)i * NPAD + j] = __float2bfloat16(o);
    }
}

// ---------------------------------------------------------------- transpose feature
// X (nvalid x 128 f32) -> XT (128 x NPAD bf16), zero-fill k >= nvalid
__global__ __launch_bounds__(256) void transpose_feat(
    const float* __restrict__ X, int nvalid, __hip_bfloat16* __restrict__ XT)
{
    __shared__ float Ts[32][33];
    const int k0 = blockIdx.x * 32, n0 = blockIdx.y * 32;
    const int t = threadIdx.x, tr = t >> 5, tc = t & 31;
    #pragma unroll
    for (int p = 0; p < 4; ++p) {
        int k = k0 + tr + p * 8;
        Ts[tr + p * 8][tc] = (k < nvalid) ? X[(size_t)k * 128 + n0 + tc] : 0.f;
    }
    __syncthreads();
    #pragma unroll
    for (int p = 0; p < 4; ++p) {
        int n = tr + p * 8;
        XT[(size_t)(n0 + n) * NPAD + k0 + tc] = __float2bfloat16(Ts[tc][n]);
    }
}

// ---------------------------------------------------------------- GEMM (B^T layout)
// C[m,n] = sum_k A[m,k]*BT[n,k].  Tile 128x128, BK=32, 4 waves (2x2), 4x4 frags.
// EPI 0: plain f32 store (full padded tile). EPI 1: sigmoid + bounds.
template<int EPI>
__global__ __launch_bounds__(256, 2) void gemm_bt(
    const __hip_bfloat16* __restrict__ A, const __hip_bfloat16* __restrict__ BT,
    float* __restrict__ C, int Kchunk, int lda, int ldb, int ldc,
    size_t zstride, int Mvalid, int Nvalid)
{
    constexpr int LDK = 40;  // padded LDS K-stride (bf16 elems): conflict-free b128 reads
    __shared__ __align__(16) __hip_bfloat16 As[128 * LDK];
    __shared__ __align__(16) __hip_bfloat16 Bs[128 * LDK];
    const int t = threadIdx.x;
    const int lane = t & 63;
    const int w = t >> 6;
    const int wm = w >> 1, wn = w & 1;
    const int tm = blockIdx.y, tn = blockIdx.x;
    const int kbeg = blockIdx.z * Kchunk;
    C += (size_t)blockIdx.z * zstride;

    floatx4 acc[4][4] = {};

    for (int k0 = kbeg; k0 < kbeg + Kchunk; k0 += 32) {
        __syncthreads();
        #pragma unroll
        for (int s = 0; s < 2; ++s) {
            int sg = t + s * 256;
            int row = sg >> 2, ks = sg & 3;
            uint4 va = *reinterpret_cast<const uint4*>(
                A + (size_t)(tm * 128 + row) * lda + k0 + ks * 8);
            *reinterpret_cast<uint4*>(&As[row * LDK + ks * 8]) = va;
            uint4 vb = *reinterpret_cast<const uint4*>(
                BT + (size_t)(tn * 128 + row) * ldb + k0 + ks * 8);
            *reinterpret_cast<uint4*>(&Bs[row * LDK + ks * 8]) = vb;
        }
        __syncthreads();
        bf16x8 af[4], bfv[4];
        const int koff = (lane >> 4) * 8;
        #pragma unroll
        for (int mi = 0; mi < 4; ++mi)
            af[mi] = *reinterpret_cast<const bf16x8*>(
                &As[(wm * 64 + mi * 16 + (lane & 15)) * LDK + koff]);
        #pragma unroll
        for (int ni = 0; ni < 4; ++ni)
            bfv[ni] = *reinterpret_cast<const bf16x8*>(
                &Bs[(wn * 64 + ni * 16 + (lane & 15)) * LDK + koff]);
        #pragma unroll
        for (int mi = 0; mi < 4; ++mi)
            #pragma unroll
            for (int ni = 0; ni < 4; ++ni)
                acc[mi][ni] = __builtin_amdgcn_mfma_f32_16x16x32_bf16(
                    af[mi], bfv[ni], acc[mi][ni], 0, 0, 0);
    }

    const int r0 = tm * 128 + wm * 64 + ((lane >> 4) << 2);
    const int c0 = tn * 128 + wn * 64 + (lane & 15);
    #pragma unroll
    for (int mi = 0; mi < 4; ++mi) {
        #pragma unroll
        for (int ni = 0; ni < 4; ++ni) {
            #pragma unroll
            for (int r = 0; r < 4; ++r) {
                int row = r0 + mi * 16 + r;
                int col = c0 + ni * 16;
                float v = acc[mi][ni][r];
                if (EPI == 0) {
                    C[(size_t)row * ldc + col] = v;
                } else {
                    if (row < Mvalid && col < Nvalid)
                        C[(size_t)row * ldc + col] = 1.f / (1.f + __expf(-v));
                }
            }
        }
    }
}

// ---------------------------------------------------------------- K-split reduce
__global__ __launch_bounds__(256) void reduce_ksplit(
    const float* __restrict__ Pp, float* __restrict__ Y)
{
    const int i = blockIdx.x * 256 + threadIdx.x;  // n = NPAD*128 = 393216
    float s = 0.f;
    #pragma unroll
    for (int z = 0; z < 16; ++z) s += Pp[(size_t)z * 393216 + i];
    Y[i] = s;
}

// ---------------------------------------------------------------- attention accumulate
template<int WRITE>
__global__ __launch_bounds__(256) void accum_att(
    const float* __restrict__ Y, const float* __restrict__ ap, int k,
    float* __restrict__ acc)
{
    const int idx = blockIdx.x * 256 + threadIdx.x;  // < 3000*128
    float a0 = ap[0], a1 = ap[1], a2 = ap[2];
    float m = fmaxf(a0, fmaxf(a1, a2));
    float e0 = __expf(a0 - m), e1 = __expf(a1 - m), e2 = __expf(a2 - m);
    float att = ((k == 0) ? e0 : (k == 1) ? e1 : e2) / (e0 + e1 + e2);
    float v = att * Y[idx];
    if (WRITE) acc[idx] = v; else acc[idx] += v;
}

// ---------------------------------------------------------------- final split+cast
__global__ __launch_bounds__(256) void cast_split(
    const float* __restrict__ acc, __hip_bfloat16* __restrict__ dF,
    __hip_bfloat16* __restrict__ pF)
{
    const int idx = blockIdx.x * 256 + threadIdx.x;  // < 1024*128 + 2048*128
    if (idx < 1024 * 128) {
        int r = idx >> 7;
        dF[idx] = __float2bfloat16(r < 1000 ? acc[idx] : 0.f);
    } else {
        int j = idx - 1024 * 128;
        int r = j >> 7;
        pF[j] = __float2bfloat16(r < 2000 ? acc[(size_t)(1000 + r) * 128 + (j & 127)] : 0.f);
    }
}

// ================================================================ launch
extern "C" void kernel_launch(void* const* d_in, const int* in_sizes, int n_in,
                              void* d_out, int out_size, void* d_ws, size_t ws_size,
                              hipStream_t stream)
{
    const float* A     = (const float*)d_in[0];
    const float* DTI   = (const float*)d_in[1];
    const float* drugS = (const float*)d_in[2];
    const float* protS = (const float*)d_in[3];
    const float* w0a   = (const float*)d_in[4];
    const float* w0b   = (const float*)d_in[5];
    const float* w1g   = (const float*)d_in[6];
    const float* ap    = (const float*)d_in[7];
    const float* wd1 = (const float*)d_in[10]; const float* bd1 = (const float*)d_in[11];
    const float* wd2 = (const float*)d_in[12]; const float* bd2 = (const float*)d_in[13];
    const float* wd3 = (const float*)d_in[14]; const float* bd3 = (const float*)d_in[15];
    const float* wp1 = (const float*)d_in[16]; const float* bp1 = (const float*)d_in[17];
    const float* wp2 = (const float*)d_in[18]; const float* bp2 = (const float*)d_in[19];
    const float* wp3 = (const float*)d_in[20]; const float* bp3 = (const float*)d_in[21];
    float* out = (float*)d_out;

    const size_t SQ_BF = (size_t)NPAD * NPAD * 2;   // 18,874,368
    const size_t SQ_F  = (size_t)NPAD * NPAD * 4;   // 37,748,736
    char* p = (char*)d_ws;
    auto alloc = [&](size_t sz) { char* r = p; p += sz; return r; };
    __hip_bfloat16* sdti = (__hip_bfloat16*)alloc(SQ_BF);
    __hip_bfloat16* a0b  = (__hip_bfloat16*)alloc(SQ_BF);
    __hip_bfloat16* b0T  = (__hip_bfloat16*)alloc(SQ_BF);
    __hip_bfloat16* g1T  = (__hip_bfloat16*)alloc(SQ_BF);
    float* Hf  = (float*)alloc(SQ_F);               // also hop K-split partials
    float* fa  = (float*)alloc((size_t)NPAD * 128 * 4);
    float* fb  = (float*)alloc((size_t)NPAD * 128 * 4);
    float* conv= (float*)alloc((size_t)NPAD * 128 * 4);
    __hip_bfloat16* XT  = (__hip_bfloat16*)alloc((size_t)128 * NPAD * 2);
    __hip_bfloat16* XT2 = (__hip_bfloat16*)alloc((size_t)128 * NPAD * 2);
    float* degv = (float*)alloc((size_t)NPAD * 4);
    __hip_bfloat16* dF = (__hip_bfloat16*)alloc((size_t)1024 * 128 * 2);
    __hip_bfloat16* pF = (__hip_bfloat16*)alloc((size_t)2048 * 128 * 2);
    if ((size_t)(p - (char*)d_ws) > ws_size) return;  // workspace too small: fail loud

    // ---- MLPs: feature -> fb (rows 0..999 drug, 1000..2999 protein)
    mlp_layer<<<125, 256, 0, stream>>>(drugS, wd1, bd1, fb, 1000);
    mlp_layer<<<250, 256, 0, stream>>>(protS, wp1, bp1, fb + 1000 * 128, 2000);
    mlp_layer<<<125, 256, 0, stream>>>(fb, wd2, bd2, fa, 1000);
    mlp_layer<<<250, 256, 0, stream>>>(fb + 1000 * 128, wp2, bp2, fa + 1000 * 128, 2000);
    mlp_layer<<<125, 256, 0, stream>>>(fa, wd3, bd3, fb, 1000);
    mlp_layer<<<250, 256, 0, stream>>>(fa + 1000 * 128, wp3, bp3, fb + 1000 * 128, 2000);

    // ---- DTI path: S_DTI then two hops -> conv (WRITE with att[0])
    rowdeg<1><<<NPAD, 256, 0, stream>>>(DTI, 3000, 3000, degv);
    scale_cast<1><<<dim3(3, NPAD), 256, 0, stream>>>(DTI, 3000, 3000, degv, sdti);
    transpose_feat<<<dim3(96, 4), 256, 0, stream>>>(fb, 3000, XT);
    gemm_bt<0><<<dim3(1, 24, 16), 256, 0, stream>>>(sdti, XT, Hf, 192, NPAD, NPAD, 128, 393216, 0, 0);
    reduce_ksplit<<<1536, 256, 0, stream>>>(Hf, fa);
    transpose_feat<<<dim3(96, 4), 256, 0, stream>>>(fa, 3000, XT2);
    gemm_bt<0><<<dim3(1, 24, 16), 256, 0, stream>>>(sdti, XT2, Hf, 192, NPAD, NPAD, 128, 393216, 0, 0);
    reduce_ksplit<<<1536, 256, 0, stream>>>(Hf, fa);
    accum_att<1><<<1500, 256, 0, stream>>>(fa, ap, 0, conv);

    // ---- per GT channel
    for (int c = 0; c < 2; ++c) {
        gtconv_chan<<<dim3(96, 96), 256, 0, stream>>>(A, w0a, w0b, w1g, c, a0b, b0T, g1T);
        // H = a0 @ b0
        gemm_bt<0><<<dim3(24, 24, 1), 256, 0, stream>>>(a0b, b0T, Hf, NPAD, NPAD, NPAD, NPAD, 0, 0, 0);
        // Hn = rownorm(H + I) -> bf16 (into a0 buffer)
        rowdeg<0><<<NPAD, 256, 0, stream>>>(Hf, NPAD, 3000, degv);
        scale_cast<0><<<dim3(3, NPAD), 256, 0, stream>>>(Hf, NPAD, 3000, degv, a0b);
        // adj = Hn @ g1   (into Hf buffer)
        gemm_bt<0><<<dim3(24, 24, 1), 256, 0, stream>>>(a0b, g1T, Hf, NPAD, NPAD, NPAD, NPAD, 0, 0, 0);
        // S = D^-1/2 (adj + 2I) D^-1/2 -> bf16 (into b0T buffer)
        rowdeg<1><<<NPAD, 256, 0, stream>>>(Hf, NPAD, 3000, degv);
        scale_cast<1><<<dim3(3, NPAD), 256, 0, stream>>>(Hf, NPAD, 3000, degv, b0T);
        // two SGC hops
        transpose_feat<<<dim3(96, 4), 256, 0, stream>>>(fb, 3000, XT);
        gemm_bt<0><<<dim3(1, 24, 16), 256, 0, stream>>>(b0T, XT, Hf, 192, NPAD, NPAD, 128, 393216, 0, 0);
        reduce_ksplit<<<1536, 256, 0, stream>>>(Hf, fa);
        transpose_feat<<<dim3(96, 4), 256, 0, stream>>>(fa, 3000, XT2);
        gemm_bt<0><<<dim3(1, 24, 16), 256, 0, stream>>>(b0T, XT2, Hf, 192, NPAD, NPAD, 128, 393216, 0, 0);
        reduce_ksplit<<<1536, 256, 0, stream>>>(Hf, fa);
        accum_att<0><<<1500, 256, 0, stream>>>(fa, ap, c + 1, conv);
    }

    // ---- final: sigmoid(drug @ prot^T)
    cast_split<<<1536, 256, 0, stream>>>(conv, dF, pF);
    gemm_bt<1><<<dim3(16, 8, 1), 256, 0, stream>>>(dF, pF, out, 128, 128, 128, 2000, 0, 1000, 2000);
}

// Round 2
// 728.424 us; speedup vs baseline: 1.2389x; 1.2389x over previous
//
#include <hip/hip_runtime.h>
#include <hip/hip_bf16.h>

typedef __attribute__((ext_vector_type(8))) __bf16 bf16x8;
typedef __attribute__((ext_vector_type(4))) float floatx4;

#define NVALID 3000
#define NPAD   3072
#define FEA    128

// async global->LDS, 16B per lane, wave-uniform LDS base (lane l lands at base + l*16)
__device__ __forceinline__ void gload16(const void* g, void* l) {
    __builtin_amdgcn_global_load_lds(
        (const __attribute__((address_space(1))) void*)g,
        (__attribute__((address_space(3))) void*)l,
        16, 0, 0);
}

// ---------------------------------------------------------------- MLP layer (drug+prot in one launch)
// rows 0..999 use Wd/bd from Xd, rows 1000..2999 use Wp/bp from Xp. grid = 375 blocks.
__global__ __launch_bounds__(256) void mlp_layer2(
    const float* __restrict__ Xd, const float* __restrict__ Xp,
    const float* __restrict__ Wd, const float* __restrict__ bd,
    const float* __restrict__ Wp, const float* __restrict__ bp,
    float* __restrict__ Y)
{
    const bool isP = blockIdx.x >= 125;
    const float* X = isP ? Xp : Xd;
    const float* W = isP ? Wp : Wd;
    const float* b = isP ? bp : bd;
    const int m0loc = (isP ? (blockIdx.x - 125) : blockIdx.x) * 8;
    const int m0out = blockIdx.x * 8;

    __shared__ float Xs[8][128];
    const int t = threadIdx.x;
    for (int s2 = t; s2 < 1024; s2 += 256) {
        int r = s2 >> 7, ii = s2 & 127;
        Xs[r][ii] = X[(size_t)(m0loc + r) * 128 + ii];
    }
    __syncthreads();
    const int o = t & 127, rh = t >> 7;
    float a0 = 0.f, a1 = 0.f, a2 = 0.f, a3 = 0.f;
    const float* wrow = W + (size_t)o * 128;
    for (int i = 0; i < 128; ++i) {
        float w = wrow[i];
        a0 += Xs[rh + 0][i] * w;
        a1 += Xs[rh + 2][i] * w;
        a2 += Xs[rh + 4][i] * w;
        a3 += Xs[rh + 6][i] * w;
    }
    const float bo = b[o];
    Y[(size_t)(m0out + rh + 0) * 128 + o] = fmaxf(a0 + bo, 0.f);
    Y[(size_t)(m0out + rh + 2) * 128 + o] = fmaxf(a1 + bo, 0.f);
    Y[(size_t)(m0out + rh + 4) * 128 + o] = fmaxf(a2 + bo, 0.f);
    Y[(size_t)(m0out + rh + 6) * 128 + o] = fmaxf(a3 + bo, 0.f);
}

// ---------------------------------------------------------------- gtconv
__device__ __forceinline__ void softmax5(const float* __restrict__ w, float* s)
{
    float m = w[0];
    #pragma unroll
    for (int e = 1; e < 5; ++e) m = fmaxf(m, w[e]);
    float sum = 0.f;
    #pragma unroll
    for (int e = 0; e < 5; ++e) { s[e] = __expf(w[e] - m); sum += s[e]; }
    float r = 1.f / sum;
    #pragma unroll
    for (int e = 0; e < 5; ++e) s[e] *= r;
}

// One channel: a0 (row-major), b0^T, g1^T  all (NPAD x NPAD) bf16, zero padded.
__global__ __launch_bounds__(256) void gtconv_chan(
    const float* __restrict__ A, const float* __restrict__ w0a,
    const float* __restrict__ w0b, const float* __restrict__ w1, int c,
    __hip_bfloat16* __restrict__ a0, __hip_bfloat16* __restrict__ bT,
    __hip_bfloat16* __restrict__ gT)
{
    float sa[5], sb[5], sg[5];
    softmax5(w0a + c * 5, sa);
    softmax5(w0b + c * 5, sb);
    softmax5(w1 + c * 5, sg);

    __shared__ float At[5][32][33];
    const int bi = blockIdx.y * 32, bj = blockIdx.x * 32;
    const int t = threadIdx.x, tr = t >> 5, tc = t & 31;

    for (int e = 0; e < 5; ++e) {
        #pragma unroll
        for (int p = 0; p < 4; ++p) {
            int i = tr + p * 8;
            int gi = bi + i, gj = bj + tc;
            At[e][i][tc] = (gi < NVALID && gj < NVALID)
                         ? A[(size_t)e * 9000000 + (size_t)gi * 3000 + gj] : 0.f;
        }
    }
    __syncthreads();
    #pragma unroll
    for (int p = 0; p < 4; ++p) {
        int i = tr + p * 8;
        float va = 0.f;
        #pragma unroll
        for (int e = 0; e < 5; ++e) va += sa[e] * At[e][i][tc];
        a0[(size_t)(bi + i) * NPAD + bj + tc] = __float2bfloat16(va);
    }
    #pragma unroll
    for (int p = 0; p < 4; ++p) {
        int jj = tr + p * 8;
        float vb = 0.f, vg = 0.f;
        #pragma unroll
        for (int e = 0; e < 5; ++e) {
            float x = At[e][tc][jj];
            vb += sb[e] * x; vg += sg[e] * x;
        }
        bT[(size_t)(bj + jj) * NPAD + bi + tc] = __float2bfloat16(vb);
        gT[(size_t)(bj + jj) * NPAD + bi + tc] = __float2bfloat16(vg);
    }
}

// ---------------------------------------------------------------- row degree
// MODE 0: rownorm  -> out = 1/(rowsum+1)
// MODE 1: sgc      -> out = rsqrt(rowsum+2)
template<int MODE>
__global__ __launch_bounds__(256) void rowdeg(
    const float* __restrict__ src, int ld, int nvalid, float* __restrict__ outv)
{
    const int i = blockIdx.x, t = threadIdx.x;
    float s = 0.f;
    if (i < nvalid)
        for (int j = t; j < nvalid; j += 256) s += src[(size_t)i * ld + j];
    #pragma unroll
    for (int off = 32; off > 0; off >>= 1) s += __shfl_down(s, off);
    __shared__ float red[4];
    if ((t & 63) == 0) red[t >> 6] = s;
    __syncthreads();
    if (t == 0) {
        float tot = red[0] + red[1] + red[2] + red[3];
        outv[i] = (MODE == 0) ? 1.f / (tot + 1.f) : rsqrtf(tot + 2.f);
    }
}

// MODE 0: dst = (src + I) * vec[i]          (row-normalize)
// MODE 1: dst = (src + 2I) * vec[i]*vec[j]  (sym sgc normalize)
template<int MODE>
__global__ __launch_bounds__(256) void scale_cast(
    const float* __restrict__ src, int lds_, int nvalid,
    const float* __restrict__ vec, __hip_bfloat16* __restrict__ dst)
{
    const int i = blockIdx.y;
    const int j0 = (blockIdx.x * 256 + threadIdx.x) * 4;
    const float vi = vec[i];
    float v[4];
    if (i < nvalid && j0 + 3 < nvalid) {
        float4 f = *reinterpret_cast<const float4*>(src + (size_t)i * lds_ + j0);
        v[0] = f.x; v[1] = f.y; v[2] = f.z; v[3] = f.w;
    } else {
        #pragma unroll
        for (int u = 0; u < 4; ++u) {
            int j = j0 + u;
            v[u] = (i < nvalid && j < nvalid) ? src[(size_t)i * lds_ + j] : 0.f;
        }
    }
    #pragma unroll
    for (int u = 0; u < 4; ++u) {
        int j = j0 + u;
        if (j == i && i < nvalid) v[u] += (MODE == 0) ? 1.f : 2.f;
        if (MODE == 0) v[u] *= vi;
        else           v[u] *= vi * vec[j];
    }
    __align__(8) __hip_bfloat16 h[4];
    #pragma unroll
    for (int u = 0; u < 4; ++u) h[u] = __float2bfloat16(v[u]);
    *reinterpret_cast<uint2*>(&dst[(size_t)i * NPAD + j0]) =
        *reinterpret_cast<const uint2*>(h);
}

// ---------------------------------------------------------------- transpose feature
// X (nvalid x 128 f32) -> XT (128 x NPAD bf16), zero-fill k >= nvalid
__global__ __launch_bounds__(256) void transpose_feat(
    const float* __restrict__ X, int nvalid, __hip_bfloat16* __restrict__ XT)
{
    __shared__ float Ts[32][33];
    const int k0 = blockIdx.x * 32, n0 = blockIdx.y * 32;
    const int t = threadIdx.x, tr = t >> 5, tc = t & 31;
    #pragma unroll
    for (int p = 0; p < 4; ++p) {
        int k = k0 + tr + p * 8;
        Ts[tr + p * 8][tc] = (k < nvalid) ? X[(size_t)k * 128 + n0 + tc] : 0.f;
    }
    __syncthreads();
    #pragma unroll
    for (int p = 0; p < 4; ++p) {
        int n = tr + p * 8;
        XT[(size_t)(n0 + n) * NPAD + k0 + tc] = __float2bfloat16(Ts[tc][n]);
    }
}

// ---------------------------------------------------------------- GEMM (B^T layout), m97 structure
// C[m,n] = sum_k A[m,k]*BT[n,k]. Tile 128x128, BK=32, 4 waves (2x2), 4x4 frags.
// global_load_lds width=16 into linear [128][32] LDS (no pad: gload_lds needs
// dest linear in lane order). EPI 0: plain f32 store. EPI 1: sigmoid + bounds.
template<int EPI>
__global__ __launch_bounds__(256, 3) void gemm_bt(
    const __hip_bfloat16* __restrict__ A, const __hip_bfloat16* __restrict__ BT,
    float* __restrict__ C, int Kchunk, int lda, int ldb, int ldc,
    size_t zstride, int Mvalid, int Nvalid)
{
    __shared__ __align__(16) __hip_bfloat16 As[128 * 32];
    __shared__ __align__(16) __hip_bfloat16 Bs[128 * 32];
    const int t = threadIdx.x;
    const int lane = t & 63;
    const int w = t >> 6;
    const int wm = w >> 1, wn = w & 1;
    const int tm = blockIdx.y, tn = blockIdx.x;
    const int kbeg = blockIdx.z * Kchunk;
    C += (size_t)blockIdx.z * zstride;

    // staging: wave w owns rows [32w, 32w+32). chunk = 64 lanes x 16B = 16 rows.
    // lane l -> row 32w + (l>>2), k-elems [(l&3)*8, +8): LDS elem w*1024 + 8l (linear).
    const int srow = lane >> 2;
    const int skg  = (lane & 3) * 8;
    const __hip_bfloat16* Ag = A  + (size_t)(tm * 128 + w * 32 + srow) * lda + skg;
    const __hip_bfloat16* Bg = BT + (size_t)(tn * 128 + w * 32 + srow) * ldb + skg;
    __hip_bfloat16* Al0 = &As[w * 1024];
    __hip_bfloat16* Al1 = &As[w * 1024 + 512];
    __hip_bfloat16* Bl0 = &Bs[w * 1024];
    __hip_bfloat16* Bl1 = &Bs[w * 1024 + 512];

    floatx4 acc[4][4] = {};

    for (int k0 = kbeg; k0 < kbeg + Kchunk; k0 += 32) {
        __syncthreads();                      // prev iter's LDS reads done
        gload16(Ag + k0,            Al0);
        gload16(Ag + 16 * lda + k0, Al1);
        gload16(Bg + k0,            Bl0);
        gload16(Bg + 16 * ldb + k0, Bl1);
        __syncthreads();                      // drains vmcnt(0): tiles landed

        bf16x8 af[4], bfv[4];
        const int koff = (lane >> 4) * 8;
        #pragma unroll
        for (int mi = 0; mi < 4; ++mi)
            af[mi] = *reinterpret_cast<const bf16x8*>(
                &As[(wm * 64 + mi * 16 + (lane & 15)) * 32 + koff]);
        #pragma unroll
        for (int ni = 0; ni < 4; ++ni)
            bfv[ni] = *reinterpret_cast<const bf16x8*>(
                &Bs[(wn * 64 + ni * 16 + (lane & 15)) * 32 + koff]);
        #pragma unroll
        for (int mi = 0; mi < 4; ++mi)
            #pragma unroll
            for (int ni = 0; ni < 4; ++ni)
                acc[mi][ni] = __builtin_amdgcn_mfma_f32_16x16x32_bf16(
                    af[mi], bfv[ni], acc[mi][ni], 0, 0, 0);
    }

    const int r0 = tm * 128 + wm * 64 + ((lane >> 4) << 2);
    const int c0 = tn * 128 + wn * 64 + (lane & 15);
    #pragma unroll
    for (int mi = 0; mi < 4; ++mi) {
        #pragma unroll
        for (int ni = 0; ni < 4; ++ni) {
            #pragma unroll
            for (int r = 0; r < 4; ++r) {
                int row = r0 + mi * 16 + r;
                int col = c0 + ni * 16;
                float v = acc[mi][ni][r];
                if (EPI == 0) {
                    C[(size_t)row * ldc + col] = v;
                } else {
                    if (row < Mvalid && col < Nvalid)
                        C[(size_t)row * ldc + col] = 1.f / (1.f + __expf(-v));
                }
            }
        }
    }
}

// ---------------------------------------------------------------- K-split reduce (hop 1)
__global__ __launch_bounds__(256) void reduce_ksplit(
    const float* __restrict__ Pp, float* __restrict__ Y)
{
    const int i = blockIdx.x * 256 + threadIdx.x;  // NPAD*128 = 393216
    float s = 0.f;
    #pragma unroll
    for (int z = 0; z < 16; ++z) s += Pp[(size_t)z * 393216 + i];
    Y[i] = s;
}

// ---------------------------------------------------------------- K-split reduce + attention (hop 2)
template<int WRITE>
__global__ __launch_bounds__(256) void reduce_att(
    const float* __restrict__ Pp, const float* __restrict__ ap, int k,
    float* __restrict__ conv)
{
    const int idx = blockIdx.x * 256 + threadIdx.x;  // grid 1500 -> 3000*128
    float s = 0.f;
    #pragma unroll
    for (int z = 0; z < 16; ++z) s += Pp[(size_t)z * 393216 + idx];
    float a0 = ap[0], a1 = ap[1], a2 = ap[2];
    float m = fmaxf(a0, fmaxf(a1, a2));
    float e0 = __expf(a0 - m), e1 = __expf(a1 - m), e2 = __expf(a2 - m);
    float att = ((k == 0) ? e0 : (k == 1) ? e1 : e2) / (e0 + e1 + e2);
    float v = att * s;
    if (WRITE) conv[idx] = v; else conv[idx] += v;
}

// ---------------------------------------------------------------- final split+cast
__global__ __launch_bounds__(256) void cast_split(
    const float* __restrict__ acc, __hip_bfloat16* __restrict__ dF,
    __hip_bfloat16* __restrict__ pF)
{
    const int idx = blockIdx.x * 256 + threadIdx.x;  // < 1024*128 + 2048*128
    if (idx < 1024 * 128) {
        int r = idx >> 7;
        dF[idx] = __float2bfloat16(r < 1000 ? acc[idx] : 0.f);
    } else {
        int j = idx - 1024 * 128;
        int r = j >> 7;
        pF[j] = __float2bfloat16(r < 2000 ? acc[(size_t)(1000 + r) * 128 + (j & 127)] : 0.f);
    }
}

// ================================================================ launch
extern "C" void kernel_launch(void* const* d_in, const int* in_sizes, int n_in,
                              void* d_out, int out_size, void* d_ws, size_t ws_size,
                              hipStream_t stream)
{
    const float* A     = (const float*)d_in[0];
    const float* DTI   = (const float*)d_in[1];
    const float* drugS = (const float*)d_in[2];
    const float* protS = (const float*)d_in[3];
    const float* w0a   = (const float*)d_in[4];
    const float* w0b   = (const float*)d_in[5];
    const float* w1g   = (const float*)d_in[6];
    const float* ap    = (const float*)d_in[7];
    const float* wd1 = (const float*)d_in[10]; const float* bd1 = (const float*)d_in[11];
    const float* wd2 = (const float*)d_in[12]; const float* bd2 = (const float*)d_in[13];
    const float* wd3 = (const float*)d_in[14]; const float* bd3 = (const float*)d_in[15];
    const float* wp1 = (const float*)d_in[16]; const float* bp1 = (const float*)d_in[17];
    const float* wp2 = (const float*)d_in[18]; const float* bp2 = (const float*)d_in[19];
    const float* wp3 = (const float*)d_in[20]; const float* bp3 = (const float*)d_in[21];
    float* out = (float*)d_out;

    const size_t SQ_BF = (size_t)NPAD * NPAD * 2;   // 18,874,368
    const size_t SQ_F  = (size_t)NPAD * NPAD * 4;   // 37,748,736
    char* p = (char*)d_ws;
    auto alloc = [&](size_t sz) { char* r = p; p += sz; return r; };
    __hip_bfloat16* sdti = (__hip_bfloat16*)alloc(SQ_BF);
    __hip_bfloat16* a0b  = (__hip_bfloat16*)alloc(SQ_BF);
    __hip_bfloat16* b0T  = (__hip_bfloat16*)alloc(SQ_BF);
    __hip_bfloat16* g1T  = (__hip_bfloat16*)alloc(SQ_BF);
    float* Hf  = (float*)alloc(SQ_F);               // also hop K-split partials
    float* fa  = (float*)alloc((size_t)NPAD * 128 * 4);
    float* fb  = (float*)alloc((size_t)NPAD * 128 * 4);
    float* conv= (float*)alloc((size_t)NPAD * 128 * 4);
    __hip_bfloat16* XTF = (__hip_bfloat16*)alloc((size_t)128 * NPAD * 2);
    __hip_bfloat16* XT2 = (__hip_bfloat16*)alloc((size_t)128 * NPAD * 2);
    float* degv = (float*)alloc((size_t)NPAD * 4);
    __hip_bfloat16* dF = (__hip_bfloat16*)alloc((size_t)1024 * 128 * 2);
    __hip_bfloat16* pF = (__hip_bfloat16*)alloc((size_t)2048 * 128 * 2);
    if ((size_t)(p - (char*)d_ws) > ws_size) return;  // workspace too small: fail loud

    // ---- MLPs: feature -> fb (rows 0..999 drug, 1000..2999 protein)
    mlp_layer2<<<375, 256, 0, stream>>>(drugS, protS, wd1, bd1, wp1, bp1, fb);
    mlp_layer2<<<375, 256, 0, stream>>>(fb, fb + 1000 * 128, wd2, bd2, wp2, bp2, fa);
    mlp_layer2<<<375, 256, 0, stream>>>(fa, fa + 1000 * 128, wd3, bd3, wp3, bp3, fb);

    // shared transpose of the (fixed) feature matrix, used by all three paths' hop 1
    transpose_feat<<<dim3(96, 4), 256, 0, stream>>>(fb, 3000, XTF);

    // ---- DTI path: S_DTI then two hops -> conv (WRITE with att[0])
    rowdeg<1><<<NPAD, 256, 0, stream>>>(DTI, 3000, 3000, degv);
    scale_cast<1><<<dim3(3, NPAD), 256, 0, stream>>>(DTI, 3000, 3000, degv, sdti);
    gemm_bt<0><<<dim3(1, 24, 16), 256, 0, stream>>>(sdti, XTF, Hf, 192, NPAD, NPAD, 128, 393216, 0, 0);
    reduce_ksplit<<<1536, 256, 0, stream>>>(Hf, fa);
    transpose_feat<<<dim3(96, 4), 256, 0, stream>>>(fa, 3000, XT2);
    gemm_bt<0><<<dim3(1, 24, 16), 256, 0, stream>>>(sdti, XT2, Hf, 192, NPAD, NPAD, 128, 393216, 0, 0);
    reduce_att<1><<<1500, 256, 0, stream>>>(Hf, ap, 0, conv);

    // ---- per GT channel
    for (int c = 0; c < 2; ++c) {
        gtconv_chan<<<dim3(96, 96), 256, 0, stream>>>(A, w0a, w0b, w1g, c, a0b, b0T, g1T);
        // H = a0 @ b0
        gemm_bt<0><<<dim3(24, 24, 1), 256, 0, stream>>>(a0b, b0T, Hf, NPAD, NPAD, NPAD, NPAD, 0, 0, 0);
        // Hn = rownorm(H + I) -> bf16 (into a0 buffer)
        rowdeg<0><<<NPAD, 256, 0, stream>>>(Hf, NPAD, 3000, degv);
        scale_cast<0><<<dim3(3, NPAD), 256, 0, stream>>>(Hf, NPAD, 3000, degv, a0b);
        // adj = Hn @ g1   (into Hf buffer)
        gemm_bt<0><<<dim3(24, 24, 1), 256, 0, stream>>>(a0b, g1T, Hf, NPAD, NPAD, NPAD, NPAD, 0, 0, 0);
        // S = D^-1/2 (adj + 2I) D^-1/2 -> bf16 (into b0T buffer)
        rowdeg<1><<<NPAD, 256, 0, stream>>>(Hf, NPAD, 3000, degv);
        scale_cast<1><<<dim3(3, NPAD), 256, 0, stream>>>(Hf, NPAD, 3000, degv, b0T);
        // two SGC hops
        gemm_bt<0><<<dim3(1, 24, 16), 256, 0, stream>>>(b0T, XTF, Hf, 192, NPAD, NPAD, 128, 393216, 0, 0);
        reduce_ksplit<<<1536, 256, 0, stream>>>(Hf, fa);
        transpose_feat<<<dim3(96, 4), 256, 0, stream>>>(fa, 3000, XT2);
        gemm_bt<0><<<dim3(1, 24, 16), 256, 0, stream>>>(b0T, XT2, Hf, 192, NPAD, NPAD, 128, 393216, 0, 0);
        reduce_att<0><<<1500, 256, 0, stream>>>(Hf, ap, c + 1, conv);
    }

    // ---- final: sigmoid(drug @ prot^T)
    cast_split<<<1536, 256, 0, stream>>>(conv, dF, pF);
    gemm_bt<1><<<dim3(16, 8, 1), 256, 0, stream>>>(dF, pF, out, 128, 128, 128, 2000, 0, 1000, 2000);
}

// Round 4
// 630.222 us; speedup vs baseline: 1.4320x; 1.1558x over previous
//
#include <hip/hip_runtime.h>
#include <hip/hip_bf16.h>

typedef __attribute__((ext_vector_type(8))) __bf16 bf16x8;
typedef __attribute__((ext_vector_type(4))) float floatx4;

#define NVALID 3000
#define NPAD   3072
#define FEA    128

// async global->LDS, 16B per lane, wave-uniform LDS base (lane l lands at base + l*16)
__device__ __forceinline__ void gload16(const void* g, void* l) {
    __builtin_amdgcn_global_load_lds(
        (const __attribute__((address_space(1))) void*)g,
        (__attribute__((address_space(3))) void*)l,
        16, 0, 0);
}

// ---------------------------------------------------------------- MLP layer (drug+prot in one launch)
__global__ __launch_bounds__(256) void mlp_layer2(
    const float* __restrict__ Xd, const float* __restrict__ Xp,
    const float* __restrict__ Wd, const float* __restrict__ bd,
    const float* __restrict__ Wp, const float* __restrict__ bp,
    float* __restrict__ Y)
{
    const bool isP = blockIdx.x >= 125;
    const float* X = isP ? Xp : Xd;
    const float* W = isP ? Wp : Wd;
    const float* b = isP ? bp : bd;
    const int m0loc = (isP ? (blockIdx.x - 125) : blockIdx.x) * 8;
    const int m0out = blockIdx.x * 8;

    __shared__ float Xs[8][128];
    const int t = threadIdx.x;
    for (int s2 = t; s2 < 1024; s2 += 256) {
        int r = s2 >> 7, ii = s2 & 127;
        Xs[r][ii] = X[(size_t)(m0loc + r) * 128 + ii];
    }
    __syncthreads();
    const int o = t & 127, rh = t >> 7;
    float a0 = 0.f, a1 = 0.f, a2 = 0.f, a3 = 0.f;
    const float* wrow = W + (size_t)o * 128;
    for (int i = 0; i < 128; ++i) {
        float w = wrow[i];
        a0 += Xs[rh + 0][i] * w;
        a1 += Xs[rh + 2][i] * w;
        a2 += Xs[rh + 4][i] * w;
        a3 += Xs[rh + 6][i] * w;
    }
    const float bo = b[o];
    Y[(size_t)(m0out + rh + 0) * 128 + o] = fmaxf(a0 + bo, 0.f);
    Y[(size_t)(m0out + rh + 2) * 128 + o] = fmaxf(a1 + bo, 0.f);
    Y[(size_t)(m0out + rh + 4) * 128 + o] = fmaxf(a2 + bo, 0.f);
    Y[(size_t)(m0out + rh + 6) * 128 + o] = fmaxf(a3 + bo, 0.f);
}

// ---------------------------------------------------------------- gtconv (BOTH channels, A read once)
__device__ __forceinline__ void softmax5(const float* __restrict__ w, float* s)
{
    float m = w[0];
    #pragma unroll
    for (int e = 1; e < 5; ++e) m = fmaxf(m, w[e]);
    float sum = 0.f;
    #pragma unroll
    for (int e = 0; e < 5; ++e) { s[e] = __expf(w[e] - m); sum += s[e]; }
    float r = 1.f / sum;
    #pragma unroll
    for (int e = 0; e < 5; ++e) s[e] *= r;
}

__global__ __launch_bounds__(256) void gtconv2(
    const float* __restrict__ A, const float* __restrict__ w0a,
    const float* __restrict__ w0b, const float* __restrict__ w1,
    __hip_bfloat16* __restrict__ a0_0, __hip_bfloat16* __restrict__ bT_0,
    __hip_bfloat16* __restrict__ gT_0,
    __hip_bfloat16* __restrict__ a0_1, __hip_bfloat16* __restrict__ bT_1,
    __hip_bfloat16* __restrict__ gT_1)
{
    float sa0[5], sb0[5], sg0[5], sa1[5], sb1[5], sg1[5];
    softmax5(w0a + 0, sa0); softmax5(w0b + 0, sb0); softmax5(w1 + 0, sg0);
    softmax5(w0a + 5, sa1); softmax5(w0b + 5, sb1); softmax5(w1 + 5, sg1);

    __shared__ float At[5][32][33];
    const int bi = blockIdx.y * 32, bj = blockIdx.x * 32;
    const int t = threadIdx.x, tr = t >> 5, tc = t & 31;

    for (int e = 0; e < 5; ++e) {
        #pragma unroll
        for (int p = 0; p < 4; ++p) {
            int i = tr + p * 8;
            int gi = bi + i, gj = bj + tc;
            At[e][i][tc] = (gi < NVALID && gj < NVALID)
                         ? A[(size_t)e * 9000000 + (size_t)gi * 3000 + gj] : 0.f;
        }
    }
    __syncthreads();
    #pragma unroll
    for (int p = 0; p < 4; ++p) {
        int i = tr + p * 8;
        float v0 = 0.f, v1 = 0.f;
        #pragma unroll
        for (int e = 0; e < 5; ++e) {
            float x = At[e][i][tc];
            v0 += sa0[e] * x; v1 += sa1[e] * x;
        }
        size_t idx = (size_t)(bi + i) * NPAD + bj + tc;
        a0_0[idx] = __float2bfloat16(v0);
        a0_1[idx] = __float2bfloat16(v1);
    }
    #pragma unroll
    for (int p = 0; p < 4; ++p) {
        int jj = tr + p * 8;
        float b0 = 0.f, g0 = 0.f, b1 = 0.f, g1 = 0.f;
        #pragma unroll
        for (int e = 0; e < 5; ++e) {
            float x = At[e][tc][jj];
            b0 += sb0[e] * x; g0 += sg0[e] * x;
            b1 += sb1[e] * x; g1 += sg1[e] * x;
        }
        size_t idx = (size_t)(bj + jj) * NPAD + bi + tc;
        bT_0[idx] = __float2bfloat16(b0);
        gT_0[idx] = __float2bfloat16(g0);
        bT_1[idx] = __float2bfloat16(b1);
        gT_1[idx] = __float2bfloat16(g1);
    }
}

// ---------------------------------------------------------------- column sums of 4 bf16 matrices
// part[z][g][c] : 24-way row-split partial column sums
__global__ __launch_bounds__(256) void colsum4(
    const __hip_bfloat16* __restrict__ M0, const __hip_bfloat16* __restrict__ M1,
    const __hip_bfloat16* __restrict__ M2, const __hip_bfloat16* __restrict__ M3,
    float* __restrict__ part)
{
    const __hip_bfloat16* M = (blockIdx.z == 0) ? M0 : (blockIdx.z == 1) ? M1
                            : (blockIdx.z == 2) ? M2 : M3;
    const int c = blockIdx.x * 256 + threadIdx.x;
    const int r0 = blockIdx.y * 128;
    float s = 0.f;
    #pragma unroll 8
    for (int r = 0; r < 128; ++r)
        s += __bfloat162float(M[(size_t)(r0 + r) * NPAD + c]);
    part[((size_t)blockIdx.z * 24 + blockIdx.y) * NPAD + c] = s;
}

__global__ __launch_bounds__(256) void colsum_fin(
    const float* __restrict__ part, float* __restrict__ v4)
{
    const int c = blockIdx.x * 256 + threadIdx.x;  // 3072
    #pragma unroll
    for (int m = 0; m < 4; ++m) {
        float s = 0.f;
        #pragma unroll
        for (int g = 0; g < 24; ++g) s += part[((size_t)m * 24 + g) * NPAD + c];
        v4[(size_t)m * NPAD + c] = s;
    }
}

// ---------------------------------------------------------------- matvec degree
// MODE 0: out = 1/(M.v + 1)     (row-norm inverse degree)
// MODE 1: out = rsqrt(M.v + 2)  (sgc inverse sqrt degree)
template<int MODE>
__global__ __launch_bounds__(256) void matvec_deg(
    const __hip_bfloat16* __restrict__ M, const float* __restrict__ v,
    float* __restrict__ outv)
{
    const size_t i = blockIdx.x;
    const int t = threadIdx.x;
    const __hip_bfloat16* row = M + i * NPAD;
    float s = 0.f;
    for (int k = t * 8; k < NPAD; k += 2048) {
        uint4 u = *reinterpret_cast<const uint4*>(&row[k]);   // 16 B = 8 bf16
        const unsigned short* us = reinterpret_cast<const unsigned short*>(&u);
        #pragma unroll
        for (int e = 0; e < 8; ++e) {
            unsigned int bits = ((unsigned int)us[e]) << 16;
            float f = __uint_as_float(bits);
            s += f * v[k + e];
        }
    }
    #pragma unroll
    for (int off = 32; off > 0; off >>= 1) s += __shfl_down(s, off);
    __shared__ float red[4];
    if ((t & 63) == 0) red[t >> 6] = s;
    __syncthreads();
    if (t == 0) {
        float tot = red[0] + red[1] + red[2] + red[3];
        outv[i] = (MODE == 0) ? 1.f / (tot + 1.f) : rsqrtf(tot + 2.f);
    }
}

// ---------------------------------------------------------------- row degree / scale (DTI f32 path only)
__global__ __launch_bounds__(256) void rowdeg_f32(
    const float* __restrict__ src, int ld, int nvalid, float* __restrict__ outv)
{
    const int i = blockIdx.x, t = threadIdx.x;
    float s = 0.f;
    if (i < nvalid)
        for (int j = t; j < nvalid; j += 256) s += src[(size_t)i * ld + j];
    #pragma unroll
    for (int off = 32; off > 0; off >>= 1) s += __shfl_down(s, off);
    __shared__ float red[4];
    if ((t & 63) == 0) red[t >> 6] = s;
    __syncthreads();
    if (t == 0) {
        float tot = red[0] + red[1] + red[2] + red[3];
        outv[i] = rsqrtf(tot + 2.f);
    }
}

__global__ __launch_bounds__(256) void scale_cast_f32(
    const float* __restrict__ src, int lds_, int nvalid,
    const float* __restrict__ vec, __hip_bfloat16* __restrict__ dst)
{
    const int i = blockIdx.y;
    const int j0 = (blockIdx.x * 256 + threadIdx.x) * 4;
    const float vi = vec[i];
    float v[4];
    if (i < nvalid && j0 + 3 < nvalid) {
        float4 f = *reinterpret_cast<const float4*>(src + (size_t)i * lds_ + j0);
        v[0] = f.x; v[1] = f.y; v[2] = f.z; v[3] = f.w;
    } else {
        #pragma unroll
        for (int u = 0; u < 4; ++u) {
            int j = j0 + u;
            v[u] = (i < nvalid && j < nvalid) ? src[(size_t)i * lds_ + j] : 0.f;
        }
    }
    #pragma unroll
    for (int u = 0; u < 4; ++u) {
        int j = j0 + u;
        if (j == i && i < nvalid) v[u] += 2.f;
        v[u] *= vi * vec[j];
    }
    __align__(8) __hip_bfloat16 h[4];
    #pragma unroll
    for (int u = 0; u < 4; ++u) h[u] = __float2bfloat16(v[u]);
    *reinterpret_cast<uint2*>(&dst[(size_t)i * NPAD + j0]) =
        *reinterpret_cast<const uint2*>(h);
}

// ---------------------------------------------------------------- transpose feature (f32 -> bf16^T)
__global__ __launch_bounds__(256) void transpose_feat(
    const float* __restrict__ X, int nvalid, __hip_bfloat16* __restrict__ XT)
{
    __shared__ float Ts[32][33];
    const int k0 = blockIdx.x * 32, n0 = blockIdx.y * 32;
    const int t = threadIdx.x, tr = t >> 5, tc = t & 31;
    #pragma unroll
    for (int p = 0; p < 4; ++p) {
        int k = k0 + tr + p * 8;
        Ts[tr + p * 8][tc] = (k < nvalid) ? X[(size_t)k * 128 + n0 + tc] : 0.f;
    }
    __syncthreads();
    #pragma unroll
    for (int p = 0; p < 4; ++p) {
        int n = tr + p * 8;
        XT[(size_t)(n0 + n) * NPAD + k0 + tc] = __float2bfloat16(Ts[tc][n]);
    }
}

// ---------------------------------------------------------------- GEMM (B^T layout), m97 structure
// C[m,n] = sum_k A[m,k]*BT[n,k]. Tile 128x128, BK=32, 4 waves, 4x4 frags.
// EPI 1: sigmoid + bounds (f32)
// EPI 2: bf16 out: (v + (r==c)) * dv[r]              (row-normalized Hn)
// EPI 3: bf16 out: (v + 2(r==c)) * dv[r]*dv[c]       (sym-normalized S)
// EPI 4: bf16 out plain (K-split partials, + z*zstride elems)
template<int EPI>
__global__ __launch_bounds__(256, 3) void gemm_bt(
    const __hip_bfloat16* __restrict__ A, const __hip_bfloat16* __restrict__ BT,
    void* __restrict__ Cv, const float* __restrict__ dv,
    int Kchunk, int lda, int ldb, int ldc,
    size_t zstride, int Mvalid, int Nvalid)
{
    __shared__ __align__(16) __hip_bfloat16 As[128 * 32];
    __shared__ __align__(16) __hip_bfloat16 Bs[128 * 32];
    const int t = threadIdx.x;
    const int lane = t & 63;
    const int w = t >> 6;
    const int wm = w >> 1, wn = w & 1;
    const int tm = blockIdx.y, tn = blockIdx.x;
    const int kbeg = blockIdx.z * Kchunk;

    const int srow = lane >> 2;
    const int skg  = (lane & 3) * 8;
    const __hip_bfloat16* Ag = A  + (size_t)(tm * 128 + w * 32 + srow) * lda + skg;
    const __hip_bfloat16* Bg = BT + (size_t)(tn * 128 + w * 32 + srow) * ldb + skg;
    __hip_bfloat16* Al0 = &As[w * 1024];
    __hip_bfloat16* Al1 = &As[w * 1024 + 512];
    __hip_bfloat16* Bl0 = &Bs[w * 1024];
    __hip_bfloat16* Bl1 = &Bs[w * 1024 + 512];

    floatx4 acc[4][4] = {};

    for (int k0 = kbeg; k0 < kbeg + Kchunk; k0 += 32) {
        __syncthreads();
        gload16(Ag + k0,            Al0);
        gload16(Ag + 16 * lda + k0, Al1);
        gload16(Bg + k0,            Bl0);
        gload16(Bg + 16 * ldb + k0, Bl1);
        __syncthreads();

        bf16x8 af[4], bfv[4];
        const int koff = (lane >> 4) * 8;
        #pragma unroll
        for (int mi = 0; mi < 4; ++mi)
            af[mi] = *reinterpret_cast<const bf16x8*>(
                &As[(wm * 64 + mi * 16 + (lane & 15)) * 32 + koff]);
        #pragma unroll
        for (int ni = 0; ni < 4; ++ni)
            bfv[ni] = *reinterpret_cast<const bf16x8*>(
                &Bs[(wn * 64 + ni * 16 + (lane & 15)) * 32 + koff]);
        #pragma unroll
        for (int mi = 0; mi < 4; ++mi)
            #pragma unroll
            for (int ni = 0; ni < 4; ++ni)
                acc[mi][ni] = __builtin_amdgcn_mfma_f32_16x16x32_bf16(
                    af[mi], bfv[ni], acc[mi][ni], 0, 0, 0);
    }

    const int r0 = tm * 128 + wm * 64 + ((lane >> 4) << 2);
    const int c0 = tn * 128 + wn * 64 + (lane & 15);
    float dvc[4];
    if (EPI == 3) {
        #pragma unroll
        for (int ni = 0; ni < 4; ++ni) dvc[ni] = dv[c0 + ni * 16];
    }
    #pragma unroll
    for (int mi = 0; mi < 4; ++mi) {
        #pragma unroll
        for (int ni = 0; ni < 4; ++ni) {
            const int col = c0 + ni * 16;
            #pragma unroll
            for (int r = 0; r < 4; ++r) {
                const int row = r0 + mi * 16 + r;
                float v = acc[mi][ni][r];
                if (EPI == 1) {
                    float* C = (float*)Cv;
                    if (row < Mvalid && col < Nvalid)
                        C[(size_t)row * ldc + col] = 1.f / (1.f + __expf(-v));
                } else if (EPI == 2) {
                    __hip_bfloat16* C = (__hip_bfloat16*)Cv;
                    float o = (v + (row == col ? 1.f : 0.f)) * dv[row];
                    C[(size_t)row * ldc + col] = __float2bfloat16(o);
                } else if (EPI == 3) {
                    __hip_bfloat16* C = (__hip_bfloat16*)Cv;
                    float o = (v + (row == col ? 2.f : 0.f)) * dv[row] * dvc[ni];
                    C[(size_t)row * ldc + col] = __float2bfloat16(o);
                } else {
                    __hip_bfloat16* C = (__hip_bfloat16*)Cv + (size_t)blockIdx.z * zstride;
                    C[(size_t)row * ldc + col] = __float2bfloat16(v);
                }
            }
        }
    }
}

// ---------------------------------------------------------------- K-split reduce + transpose (hop1 -> XT2)
__global__ __launch_bounds__(256) void reduce_trans(
    const __hip_bfloat16* __restrict__ Pp, __hip_bfloat16* __restrict__ XT)
{
    __shared__ float Ts[32][33];
    const int k0 = blockIdx.x * 32, n0 = blockIdx.y * 32;
    const int t = threadIdx.x, tr = t >> 5, tc = t & 31;
    #pragma unroll
    for (int p = 0; p < 4; ++p) {
        int k = k0 + tr + p * 8;
        float s = 0.f;
        #pragma unroll
        for (int z = 0; z < 16; ++z)
            s += __bfloat162float(Pp[(size_t)z * 393216 + (size_t)k * 128 + n0 + tc]);
        Ts[tr + p * 8][tc] = s;
    }
    __syncthreads();
    #pragma unroll
    for (int p = 0; p < 4; ++p) {
        int n = tr + p * 8;
        XT[(size_t)(n0 + n) * NPAD + k0 + tc] = __float2bfloat16(Ts[tc][n]);
    }
}

// ---------------------------------------------------------------- K-split reduce + attention (hop2 -> conv)
template<int WRITE>
__global__ __launch_bounds__(256) void reduce_att(
    const __hip_bfloat16* __restrict__ Pp, const float* __restrict__ ap, int k,
    float* __restrict__ conv)
{
    const int idx = blockIdx.x * 256 + threadIdx.x;  // grid 1500 -> 3000*128
    float s = 0.f;
    #pragma unroll
    for (int z = 0; z < 16; ++z)
        s += __bfloat162float(Pp[(size_t)z * 393216 + idx]);
    float a0 = ap[0], a1 = ap[1], a2 = ap[2];
    float m = fmaxf(a0, fmaxf(a1, a2));
    float e0 = __expf(a0 - m), e1 = __expf(a1 - m), e2 = __expf(a2 - m);
    float att = ((k == 0) ? e0 : (k == 1) ? e1 : e2) / (e0 + e1 + e2);
    float v = att * s;
    if (WRITE) conv[idx] = v; else conv[idx] += v;
}

// ---------------------------------------------------------------- final split+cast
__global__ __launch_bounds__(256) void cast_split(
    const float* __restrict__ acc, __hip_bfloat16* __restrict__ dF,
    __hip_bfloat16* __restrict__ pF)
{
    const int idx = blockIdx.x * 256 + threadIdx.x;
    if (idx < 1024 * 128) {
        int r = idx >> 7;
        dF[idx] = __float2bfloat16(r < 1000 ? acc[idx] : 0.f);
    } else {
        int j = idx - 1024 * 128;
        int r = j >> 7;
        pF[j] = __float2bfloat16(r < 2000 ? acc[(size_t)(1000 + r) * 128 + (j & 127)] : 0.f);
    }
}

// ================================================================ launch
extern "C" void kernel_launch(void* const* d_in, const int* in_sizes, int n_in,
                              void* d_out, int out_size, void* d_ws, size_t ws_size,
                              hipStream_t stream)
{
    const float* A     = (const float*)d_in[0];
    const float* DTI   = (const float*)d_in[1];
    const float* drugS = (const float*)d_in[2];
    const float* protS = (const float*)d_in[3];
    const float* w0a   = (const float*)d_in[4];
    const float* w0b   = (const float*)d_in[5];
    const float* w1g   = (const float*)d_in[6];
    const float* ap    = (const float*)d_in[7];
    const float* wd1 = (const float*)d_in[10]; const float* bd1 = (const float*)d_in[11];
    const float* wd2 = (const float*)d_in[12]; const float* bd2 = (const float*)d_in[13];
    const float* wd3 = (const float*)d_in[14]; const float* bd3 = (const float*)d_in[15];
    const float* wp1 = (const float*)d_in[16]; const float* bp1 = (const float*)d_in[17];
    const float* wp2 = (const float*)d_in[18]; const float* bp2 = (const float*)d_in[19];
    const float* wp3 = (const float*)d_in[20]; const float* bp3 = (const float*)d_in[21];
    float* out = (float*)d_out;

    const size_t SQ_BF = (size_t)NPAD * NPAD * 2;   // 18,874,368
    char* p = (char*)d_ws;
    auto alloc = [&](size_t sz) { char* r = p; p += (sz + 255) & ~(size_t)255; return r; };
    __hip_bfloat16* sdti = (__hip_bfloat16*)alloc(SQ_BF);
    __hip_bfloat16* a0c[2], *b0c[2], *g1c[2];
    for (int c = 0; c < 2; ++c) {
        a0c[c] = (__hip_bfloat16*)alloc(SQ_BF);
        b0c[c] = (__hip_bfloat16*)alloc(SQ_BF);   // becomes S_c after gemm-adj
        g1c[c] = (__hip_bfloat16*)alloc(SQ_BF);
    }
    __hip_bfloat16* HnB  = (__hip_bfloat16*)alloc(SQ_BF);
    __hip_bfloat16* part = (__hip_bfloat16*)alloc((size_t)16 * 393216 * 2);
    float* cspart = (float*)alloc((size_t)4 * 24 * NPAD * 4);
    float* v4     = (float*)alloc((size_t)4 * NPAD * 4);
    float* dinv   = (float*)alloc((size_t)NPAD * 4);
    float* rsv    = (float*)alloc((size_t)NPAD * 4);
    float* degv   = (float*)alloc((size_t)NPAD * 4);
    float* fa   = (float*)alloc((size_t)NPAD * 128 * 4);
    float* fb   = (float*)alloc((size_t)NPAD * 128 * 4);
    float* conv = (float*)alloc((size_t)NPAD * 128 * 4);
    __hip_bfloat16* XTF = (__hip_bfloat16*)alloc((size_t)128 * NPAD * 2);
    __hip_bfloat16* XT2 = (__hip_bfloat16*)alloc((size_t)128 * NPAD * 2);
    __hip_bfloat16* dF = (__hip_bfloat16*)alloc((size_t)1024 * 128 * 2);
    __hip_bfloat16* pF = (__hip_bfloat16*)alloc((size_t)2048 * 128 * 2);
    if ((size_t)(p - (char*)d_ws) > ws_size) return;  // fail loud if ws too small

    // ---- MLPs: feature -> fb
    mlp_layer2<<<375, 256, 0, stream>>>(drugS, protS, wd1, bd1, wp1, bp1, fb);
    mlp_layer2<<<375, 256, 0, stream>>>(fb, fb + 1000 * 128, wd2, bd2, wp2, bp2, fa);
    mlp_layer2<<<375, 256, 0, stream>>>(fa, fa + 1000 * 128, wd3, bd3, wp3, bp3, fb);
    transpose_feat<<<dim3(96, 4), 256, 0, stream>>>(fb, 3000, XTF);

    // ---- gtconv: both channels in one pass over A
    gtconv2<<<dim3(96, 96), 256, 0, stream>>>(A, w0a, w0b, w1g,
        a0c[0], b0c[0], g1c[0], a0c[1], b0c[1], g1c[1]);
    // column sums (= row sums of b0/g1) for degree matvecs
    colsum4<<<dim3(12, 24, 4), 256, 0, stream>>>(b0c[0], g1c[0], b0c[1], g1c[1], cspart);
    colsum_fin<<<12, 256, 0, stream>>>(cspart, v4);

    // ---- DTI path
    rowdeg_f32<<<NPAD, 256, 0, stream>>>(DTI, 3000, 3000, degv);
    scale_cast_f32<<<dim3(3, NPAD), 256, 0, stream>>>(DTI, 3000, 3000, degv, sdti);
    gemm_bt<4><<<dim3(1, 24, 16), 256, 0, stream>>>(sdti, XTF, part, nullptr, 192, NPAD, NPAD, 128, 393216, 0, 0);
    reduce_trans<<<dim3(96, 4), 256, 0, stream>>>(part, XT2);
    gemm_bt<4><<<dim3(1, 24, 16), 256, 0, stream>>>(sdti, XT2, part, nullptr, 192, NPAD, NPAD, 128, 393216, 0, 0);
    reduce_att<1><<<1500, 256, 0, stream>>>(part, ap, 0, conv);

    // ---- per GT channel
    for (int c = 0; c < 2; ++c) {
        // deg(H) = a0 . rowsum(b0) + 1  -> dinv
        matvec_deg<0><<<NPAD, 256, 0, stream>>>(a0c[c], v4 + (size_t)(2 * c) * NPAD, dinv);
        // Hn = D^-1 (a0@b0 + I)  (bf16, fused epilogue)
        gemm_bt<2><<<dim3(24, 24, 1), 256, 0, stream>>>(a0c[c], b0c[c], HnB, dinv, NPAD, NPAD, NPAD, NPAD, 0, 0, 0);
        // deg2 = Hn . rowsum(g1) + 2 -> rs
        matvec_deg<1><<<NPAD, 256, 0, stream>>>(HnB, v4 + (size_t)(2 * c + 1) * NPAD, rsv);
        // S = D2^-1/2 (Hn@g1 + 2I) D2^-1/2  (bf16, fused epilogue; into b0 buffer)
        gemm_bt<3><<<dim3(24, 24, 1), 256, 0, stream>>>(HnB, g1c[c], b0c[c], rsv, NPAD, NPAD, NPAD, NPAD, 0, 0, 0);
        // two SGC hops
        gemm_bt<4><<<dim3(1, 24, 16), 256, 0, stream>>>(b0c[c], XTF, part, nullptr, 192, NPAD, NPAD, 128, 393216, 0, 0);
        reduce_trans<<<dim3(96, 4), 256, 0, stream>>>(part, XT2);
        gemm_bt<4><<<dim3(1, 24, 16), 256, 0, stream>>>(b0c[c], XT2, part, nullptr, 192, NPAD, NPAD, 128, 393216, 0, 0);
        reduce_att<0><<<1500, 256, 0, stream>>>(part, ap, c + 1, conv);
    }

    // ---- final: sigmoid(drug @ prot^T)
    cast_split<<<1536, 256, 0, stream>>>(conv, dF, pF);
    gemm_bt<1><<<dim3(16, 8, 1), 256, 0, stream>>>(dF, pF, out, nullptr, 128, 128, 128, 2000, 0, 1000, 2000);
}

// Round 5
// 605.072 us; speedup vs baseline: 1.4915x; 1.0416x over previous
//
#include <hip/hip_runtime.h>
#include <hip/hip_bf16.h>

typedef __attribute__((ext_vector_type(8))) __bf16 bf16x8;
typedef __attribute__((ext_vector_type(4))) float floatx4;

#define NVALID 3000
#define NPAD   3072
#define FEA    128

// async global->LDS, 16B per lane, wave-uniform LDS base (lane l lands at base + l*16)
__device__ __forceinline__ void gload16(const void* g, void* l) {
    __builtin_amdgcn_global_load_lds(
        (const __attribute__((address_space(1))) void*)g,
        (__attribute__((address_space(3))) void*)l,
        16, 0, 0);
}

// ---------------------------------------------------------------- MLP layer (drug+prot in one launch)
__global__ __launch_bounds__(256) void mlp_layer2(
    const float* __restrict__ Xd, const float* __restrict__ Xp,
    const float* __restrict__ Wd, const float* __restrict__ bd,
    const float* __restrict__ Wp, const float* __restrict__ bp,
    float* __restrict__ Y)
{
    const bool isP = blockIdx.x >= 125;
    const float* X = isP ? Xp : Xd;
    const float* W = isP ? Wp : Wd;
    const float* b = isP ? bp : bd;
    const int m0loc = (isP ? (blockIdx.x - 125) : blockIdx.x) * 8;
    const int m0out = blockIdx.x * 8;

    __shared__ float Xs[8][128];
    const int t = threadIdx.x;
    for (int s2 = t; s2 < 1024; s2 += 256) {
        int r = s2 >> 7, ii = s2 & 127;
        Xs[r][ii] = X[(size_t)(m0loc + r) * 128 + ii];
    }
    __syncthreads();
    const int o = t & 127, rh = t >> 7;
    float a0 = 0.f, a1 = 0.f, a2 = 0.f, a3 = 0.f;
    const float* wrow = W + (size_t)o * 128;
    for (int i = 0; i < 128; ++i) {
        float w = wrow[i];
        a0 += Xs[rh + 0][i] * w;
        a1 += Xs[rh + 2][i] * w;
        a2 += Xs[rh + 4][i] * w;
        a3 += Xs[rh + 6][i] * w;
    }
    const float bo = b[o];
    Y[(size_t)(m0out + rh + 0) * 128 + o] = fmaxf(a0 + bo, 0.f);
    Y[(size_t)(m0out + rh + 2) * 128 + o] = fmaxf(a1 + bo, 0.f);
    Y[(size_t)(m0out + rh + 4) * 128 + o] = fmaxf(a2 + bo, 0.f);
    Y[(size_t)(m0out + rh + 6) * 128 + o] = fmaxf(a3 + bo, 0.f);
}

// ---------------------------------------------------------------- gtconv (BOTH channels, A read once)
__device__ __forceinline__ void softmax5(const float* __restrict__ w, float* s)
{
    float m = w[0];
    #pragma unroll
    for (int e = 1; e < 5; ++e) m = fmaxf(m, w[e]);
    float sum = 0.f;
    #pragma unroll
    for (int e = 0; e < 5; ++e) { s[e] = __expf(w[e] - m); sum += s[e]; }
    float r = 1.f / sum;
    #pragma unroll
    for (int e = 0; e < 5; ++e) s[e] *= r;
}

// Tile 16 rows x 128 cols. float4 loads, uint4-packed bf16 stores.
__global__ __launch_bounds__(256) void gtconv2(
    const float* __restrict__ A, const float* __restrict__ w0a,
    const float* __restrict__ w0b, const float* __restrict__ w1,
    __hip_bfloat16* __restrict__ a0_0, __hip_bfloat16* __restrict__ bT_0,
    __hip_bfloat16* __restrict__ gT_0,
    __hip_bfloat16* __restrict__ a0_1, __hip_bfloat16* __restrict__ bT_1,
    __hip_bfloat16* __restrict__ gT_1)
{
    float sa0[5], sb0[5], sg0[5], sa1[5], sb1[5], sg1[5];
    softmax5(w0a + 0, sa0); softmax5(w0b + 0, sb0); softmax5(w1 + 0, sg0);
    softmax5(w0a + 5, sa1); softmax5(w0b + 5, sb1); softmax5(w1 + 5, sg1);

    __shared__ float At[5][16][128];
    const int bi = blockIdx.y * 16;    // A row base
    const int bj = blockIdx.x * 128;   // A col base
    const int t = threadIdx.x;
    const int tc = t & 31, tr = t >> 5;        // tc: 4-col group, tr: row 0..7
    const bool colFast = (bj + 127) < NVALID;  // all 128 cols valid

    for (int e = 0; e < 5; ++e) {
        const float* Ae = A + (size_t)e * 9000000;
        #pragma unroll
        for (int p = 0; p < 2; ++p) {
            int i = tr + p * 8;
            int gi = bi + i;
            int gj = bj + tc * 4;
            float4 v = make_float4(0.f, 0.f, 0.f, 0.f);
            if (gi < NVALID) {
                if (colFast) {
                    v = *reinterpret_cast<const float4*>(Ae + (size_t)gi * 3000 + gj);
                } else {
                    float tm0 = (gj + 0 < NVALID) ? Ae[(size_t)gi * 3000 + gj + 0] : 0.f;
                    float tm1 = (gj + 1 < NVALID) ? Ae[(size_t)gi * 3000 + gj + 1] : 0.f;
                    float tm2 = (gj + 2 < NVALID) ? Ae[(size_t)gi * 3000 + gj + 2] : 0.f;
                    float tm3 = (gj + 3 < NVALID) ? Ae[(size_t)gi * 3000 + gj + 3] : 0.f;
                    v = make_float4(tm0, tm1, tm2, tm3);
                }
            }
            *reinterpret_cast<float4*>(&At[e][i][tc * 4]) = v;
        }
    }
    __syncthreads();

    // a0 (row-major): each thread 2 rows x 4 cols, packed uint2 stores
    #pragma unroll
    for (int p = 0; p < 2; ++p) {
        int i = tr + p * 8;
        float o0[4] = {0.f, 0.f, 0.f, 0.f}, o1[4] = {0.f, 0.f, 0.f, 0.f};
        #pragma unroll
        for (int e = 0; e < 5; ++e) {
            float4 x = *reinterpret_cast<const float4*>(&At[e][i][tc * 4]);
            o0[0] += sa0[e] * x.x; o0[1] += sa0[e] * x.y;
            o0[2] += sa0[e] * x.z; o0[3] += sa0[e] * x.w;
            o1[0] += sa1[e] * x.x; o1[1] += sa1[e] * x.y;
            o1[2] += sa1[e] * x.z; o1[3] += sa1[e] * x.w;
        }
        __align__(8) __hip_bfloat16 h0[4], h1[4];
        #pragma unroll
        for (int u = 0; u < 4; ++u) {
            h0[u] = __float2bfloat16(o0[u]);
            h1[u] = __float2bfloat16(o1[u]);
        }
        size_t idx = (size_t)(bi + i) * NPAD + bj + tc * 4;
        *reinterpret_cast<uint2*>(&a0_0[idx]) = *reinterpret_cast<const uint2*>(h0);
        *reinterpret_cast<uint2*>(&a0_1[idx]) = *reinterpret_cast<const uint2*>(h1);
    }

    // bT/gT (transposed): thread -> (j = t>>1, 8 i's at ih), uint4 stores (16B)
    {
        const int j  = t >> 1;
        const int ih = (t & 1) * 8;
        float vb0[8], vg0[8], vb1[8], vg1[8];
        #pragma unroll
        for (int k = 0; k < 8; ++k) { vb0[k] = vg0[k] = vb1[k] = vg1[k] = 0.f; }
        #pragma unroll
        for (int e = 0; e < 5; ++e) {
            #pragma unroll
            for (int k = 0; k < 8; ++k) {
                float x = At[e][ih + k][j];
                vb0[k] += sb0[e] * x; vg0[k] += sg0[e] * x;
                vb1[k] += sb1[e] * x; vg1[k] += sg1[e] * x;
            }
        }
        __align__(16) __hip_bfloat16 hb0[8], hg0[8], hb1[8], hg1[8];
        #pragma unroll
        for (int k = 0; k < 8; ++k) {
            hb0[k] = __float2bfloat16(vb0[k]);
            hg0[k] = __float2bfloat16(vg0[k]);
            hb1[k] = __float2bfloat16(vb1[k]);
            hg1[k] = __float2bfloat16(vg1[k]);
        }
        size_t idx = (size_t)(bj + j) * NPAD + bi + ih;
        *reinterpret_cast<uint4*>(&bT_0[idx]) = *reinterpret_cast<const uint4*>(hb0);
        *reinterpret_cast<uint4*>(&gT_0[idx]) = *reinterpret_cast<const uint4*>(hg0);
        *reinterpret_cast<uint4*>(&bT_1[idx]) = *reinterpret_cast<const uint4*>(hb1);
        *reinterpret_cast<uint4*>(&gT_1[idx]) = *reinterpret_cast<const uint4*>(hg1);
    }
}

// ---------------------------------------------------------------- column sums of 4 bf16 matrices
// part[z][g][c] : 24-way row-split partial column sums, 8 cols/thread vectorized
__global__ __launch_bounds__(256) void colsum4(
    const __hip_bfloat16* __restrict__ M0, const __hip_bfloat16* __restrict__ M1,
    const __hip_bfloat16* __restrict__ M2, const __hip_bfloat16* __restrict__ M3,
    float* __restrict__ part)
{
    const __hip_bfloat16* M = (blockIdx.z == 0) ? M0 : (blockIdx.z == 1) ? M1
                            : (blockIdx.z == 2) ? M2 : M3;
    const int c0 = blockIdx.x * 2048 + threadIdx.x * 8;
    if (c0 >= NPAD) return;
    const int r0 = blockIdx.y * 128;
    float s[8] = {0.f,0.f,0.f,0.f,0.f,0.f,0.f,0.f};
    for (int r = 0; r < 128; ++r) {
        uint4 u = *reinterpret_cast<const uint4*>(&M[(size_t)(r0 + r) * NPAD + c0]);
        const unsigned short* us = reinterpret_cast<const unsigned short*>(&u);
        #pragma unroll
        for (int e = 0; e < 8; ++e)
            s[e] += __uint_as_float(((unsigned int)us[e]) << 16);
    }
    float* dst = part + ((size_t)blockIdx.z * 24 + blockIdx.y) * NPAD + c0;
    *reinterpret_cast<float4*>(dst)     = make_float4(s[0], s[1], s[2], s[3]);
    *reinterpret_cast<float4*>(dst + 4) = make_float4(s[4], s[5], s[6], s[7]);
}

__global__ __launch_bounds__(256) void colsum_fin(
    const float* __restrict__ part, float* __restrict__ v4)
{
    const int c = blockIdx.x * 256 + threadIdx.x;  // 3072
    #pragma unroll
    for (int m = 0; m < 4; ++m) {
        float s = 0.f;
        #pragma unroll
        for (int g = 0; g < 24; ++g) s += part[((size_t)m * 24 + g) * NPAD + c];
        v4[(size_t)m * NPAD + c] = s;
    }
}

// ---------------------------------------------------------------- matvec degree
// MODE 0: out = 1/(M.v + 1)     MODE 1: out = rsqrt(M.v + 2)
template<int MODE>
__global__ __launch_bounds__(256) void matvec_deg(
    const __hip_bfloat16* __restrict__ M, const float* __restrict__ v,
    float* __restrict__ outv)
{
    const size_t i = blockIdx.x;
    const int t = threadIdx.x;
    const __hip_bfloat16* row = M + i * NPAD;
    float s = 0.f;
    for (int k = t * 8; k < NPAD; k += 2048) {
        uint4 u = *reinterpret_cast<const uint4*>(&row[k]);   // 16 B = 8 bf16
        const unsigned short* us = reinterpret_cast<const unsigned short*>(&u);
        #pragma unroll
        for (int e = 0; e < 8; ++e) {
            unsigned int bits = ((unsigned int)us[e]) << 16;
            float f = __uint_as_float(bits);
            s += f * v[k + e];
        }
    }
    #pragma unroll
    for (int off = 32; off > 0; off >>= 1) s += __shfl_down(s, off);
    __shared__ float red[4];
    if ((t & 63) == 0) red[t >> 6] = s;
    __syncthreads();
    if (t == 0) {
        float tot = red[0] + red[1] + red[2] + red[3];
        outv[i] = (MODE == 0) ? 1.f / (tot + 1.f) : rsqrtf(tot + 2.f);
    }
}

// ---------------------------------------------------------------- DTI degree (f32, float4)
__global__ __launch_bounds__(256) void rowdeg_f32(
    const float* __restrict__ src, float* __restrict__ outv)
{
    const int i = blockIdx.x, t = threadIdx.x;
    float s = 0.f;
    if (i < NVALID) {
        const float* row = src + (size_t)i * 3000;
        for (int j4 = t; j4 < 750; j4 += 256) {      // 3000 = 750 * 4
            float4 v = *reinterpret_cast<const float4*>(row + j4 * 4);
            s += v.x + v.y + v.z + v.w;
        }
    }
    #pragma unroll
    for (int off = 32; off > 0; off >>= 1) s += __shfl_down(s, off);
    __shared__ float red[4];
    if ((t & 63) == 0) red[t >> 6] = s;
    __syncthreads();
    if (t == 0) {
        float tot = red[0] + red[1] + red[2] + red[3];
        outv[i] = rsqrtf(tot + 2.f);
    }
}

__global__ __launch_bounds__(256) void scale_cast_f32(
    const float* __restrict__ src, int lds_, int nvalid,
    const float* __restrict__ vec, __hip_bfloat16* __restrict__ dst)
{
    const int i = blockIdx.y;
    const int j0 = (blockIdx.x * 256 + threadIdx.x) * 4;
    const float vi = vec[i];
    float v[4];
    if (i < nvalid && j0 + 3 < nvalid) {
        float4 f = *reinterpret_cast<const float4*>(src + (size_t)i * lds_ + j0);
        v[0] = f.x; v[1] = f.y; v[2] = f.z; v[3] = f.w;
    } else {
        #pragma unroll
        for (int u = 0; u < 4; ++u) {
            int j = j0 + u;
            v[u] = (i < nvalid && j < nvalid) ? src[(size_t)i * lds_ + j] : 0.f;
        }
    }
    #pragma unroll
    for (int u = 0; u < 4; ++u) {
        int j = j0 + u;
        if (j == i && i < nvalid) v[u] += 2.f;
        v[u] *= vi * vec[j];
    }
    __align__(8) __hip_bfloat16 h[4];
    #pragma unroll
    for (int u = 0; u < 4; ++u) h[u] = __float2bfloat16(v[u]);
    *reinterpret_cast<uint2*>(&dst[(size_t)i * NPAD + j0]) =
        *reinterpret_cast<const uint2*>(h);
}

// ---------------------------------------------------------------- transpose feature (f32 -> bf16^T)
__global__ __launch_bounds__(256) void transpose_feat(
    const float* __restrict__ X, int nvalid, __hip_bfloat16* __restrict__ XT)
{
    __shared__ float Ts[32][33];
    const int k0 = blockIdx.x * 32, n0 = blockIdx.y * 32;
    const int t = threadIdx.x, tr = t >> 5, tc = t & 31;
    #pragma unroll
    for (int p = 0; p < 4; ++p) {
        int k = k0 + tr + p * 8;
        Ts[tr + p * 8][tc] = (k < nvalid) ? X[(size_t)k * 128 + n0 + tc] : 0.f;
    }
    __syncthreads();
    #pragma unroll
    for (int p = 0; p < 4; ++p) {
        int n = tr + p * 8;
        XT[(size_t)(n0 + n) * NPAD + k0 + tc] = __float2bfloat16(Ts[tc][n]);
    }
}

// ---------------------------------------------------------------- GEMM (B^T layout), m97 structure
// EPI 1: sigmoid + bounds (f32)
// EPI 2: bf16 out: (v + (r==c)) * dv[r]
// EPI 3: bf16 out: (v + 2(r==c)) * dv[r]*dv[c]
// EPI 4: bf16 out plain (K-split partials)
template<int EPI>
__global__ __launch_bounds__(256, 3) void gemm_bt(
    const __hip_bfloat16* __restrict__ A, const __hip_bfloat16* __restrict__ BT,
    void* __restrict__ Cv, const float* __restrict__ dv,
    int Kchunk, int lda, int ldb, int ldc,
    size_t zstride, int Mvalid, int Nvalid)
{
    __shared__ __align__(16) __hip_bfloat16 As[128 * 32];
    __shared__ __align__(16) __hip_bfloat16 Bs[128 * 32];
    const int t = threadIdx.x;
    const int lane = t & 63;
    const int w = t >> 6;
    const int wm = w >> 1, wn = w & 1;
    const int tm = blockIdx.y, tn = blockIdx.x;
    const int kbeg = blockIdx.z * Kchunk;

    const int srow = lane >> 2;
    const int skg  = (lane & 3) * 8;
    const __hip_bfloat16* Ag = A  + (size_t)(tm * 128 + w * 32 + srow) * lda + skg;
    const __hip_bfloat16* Bg = BT + (size_t)(tn * 128 + w * 32 + srow) * ldb + skg;
    __hip_bfloat16* Al0 = &As[w * 1024];
    __hip_bfloat16* Al1 = &As[w * 1024 + 512];
    __hip_bfloat16* Bl0 = &Bs[w * 1024];
    __hip_bfloat16* Bl1 = &Bs[w * 1024 + 512];

    floatx4 acc[4][4] = {};

    for (int k0 = kbeg; k0 < kbeg + Kchunk; k0 += 32) {
        __syncthreads();
        gload16(Ag + k0,            Al0);
        gload16(Ag + 16 * lda + k0, Al1);
        gload16(Bg + k0,            Bl0);
        gload16(Bg + 16 * ldb + k0, Bl1);
        __syncthreads();

        bf16x8 af[4], bfv[4];
        const int koff = (lane >> 4) * 8;
        #pragma unroll
        for (int mi = 0; mi < 4; ++mi)
            af[mi] = *reinterpret_cast<const bf16x8*>(
                &As[(wm * 64 + mi * 16 + (lane & 15)) * 32 + koff]);
        #pragma unroll
        for (int ni = 0; ni < 4; ++ni)
            bfv[ni] = *reinterpret_cast<const bf16x8*>(
                &Bs[(wn * 64 + ni * 16 + (lane & 15)) * 32 + koff]);
        #pragma unroll
        for (int mi = 0; mi < 4; ++mi)
            #pragma unroll
            for (int ni = 0; ni < 4; ++ni)
                acc[mi][ni] = __builtin_amdgcn_mfma_f32_16x16x32_bf16(
                    af[mi], bfv[ni], acc[mi][ni], 0, 0, 0);
    }

    const int r0 = tm * 128 + wm * 64 + ((lane >> 4) << 2);
    const int c0 = tn * 128 + wn * 64 + (lane & 15);
    float dvc[4];
    if (EPI == 3) {
        #pragma unroll
        for (int ni = 0; ni < 4; ++ni) dvc[ni] = dv[c0 + ni * 16];
    }
    #pragma unroll
    for (int mi = 0; mi < 4; ++mi) {
        #pragma unroll
        for (int ni = 0; ni < 4; ++ni) {
            const int col = c0 + ni * 16;
            #pragma unroll
            for (int r = 0; r < 4; ++r) {
                const int row = r0 + mi * 16 + r;
                float v = acc[mi][ni][r];
                if (EPI == 1) {
                    float* C = (float*)Cv;
                    if (row < Mvalid && col < Nvalid)
                        C[(size_t)row * ldc + col] = 1.f / (1.f + __expf(-v));
                } else if (EPI == 2) {
                    __hip_bfloat16* C = (__hip_bfloat16*)Cv;
                    float o = (v + (row == col ? 1.f : 0.f)) * dv[row];
                    C[(size_t)row * ldc + col] = __float2bfloat16(o);
                } else if (EPI == 3) {
                    __hip_bfloat16* C = (__hip_bfloat16*)Cv;
                    float o = (v + (row == col ? 2.f : 0.f)) * dv[row] * dvc[ni];
                    C[(size_t)row * ldc + col] = __float2bfloat16(o);
                } else {
                    __hip_bfloat16* C = (__hip_bfloat16*)Cv + (size_t)blockIdx.z * zstride;
                    C[(size_t)row * ldc + col] = __float2bfloat16(v);
                }
            }
        }
    }
}

// ---------------------------------------------------------------- K-split reduce + transpose (hop1 -> XT2)
__global__ __launch_bounds__(256) void reduce_trans(
    const __hip_bfloat16* __restrict__ Pp, __hip_bfloat16* __restrict__ XT)
{
    __shared__ float Ts[32][33];
    const int k0 = blockIdx.x * 32, n0 = blockIdx.y * 32;
    const int t = threadIdx.x, tr = t >> 5, tc = t & 31;
    #pragma unroll
    for (int p = 0; p < 4; ++p) {
        int k = k0 + tr + p * 8;
        float s = 0.f;
        #pragma unroll
        for (int z = 0; z < 16; ++z)
            s += __bfloat162float(Pp[(size_t)z * 393216 + (size_t)k * 128 + n0 + tc]);
        Ts[tr + p * 8][tc] = s;
    }
    __syncthreads();
    #pragma unroll
    for (int p = 0; p < 4; ++p) {
        int n = tr + p * 8;
        XT[(size_t)(n0 + n) * NPAD + k0 + tc] = __float2bfloat16(Ts[tc][n]);
    }
}

// ---------------------------------------------------------------- K-split reduce + attention (hop2 -> conv)
template<int WRITE>
__global__ __launch_bounds__(256) void reduce_att(
    const __hip_bfloat16* __restrict__ Pp, const float* __restrict__ ap, int k,
    float* __restrict__ conv)
{
    const int idx = blockIdx.x * 256 + threadIdx.x;  // grid 1500 -> 3000*128
    float s = 0.f;
    #pragma unroll
    for (int z = 0; z < 16; ++z)
        s += __bfloat162float(Pp[(size_t)z * 393216 + idx]);
    float a0 = ap[0], a1 = ap[1], a2 = ap[2];
    float m = fmaxf(a0, fmaxf(a1, a2));
    float e0 = __expf(a0 - m), e1 = __expf(a1 - m), e2 = __expf(a2 - m);
    float att = ((k == 0) ? e0 : (k == 1) ? e1 : e2) / (e0 + e1 + e2);
    float v = att * s;
    if (WRITE) conv[idx] = v; else conv[idx] += v;
}

// ---------------------------------------------------------------- final split+cast
__global__ __launch_bounds__(256) void cast_split(
    const float* __restrict__ acc, __hip_bfloat16* __restrict__ dF,
    __hip_bfloat16* __restrict__ pF)
{
    const int idx = blockIdx.x * 256 + threadIdx.x;
    if (idx < 1024 * 128) {
        int r = idx >> 7;
        dF[idx] = __float2bfloat16(r < 1000 ? acc[idx] : 0.f);
    } else {
        int j = idx - 1024 * 128;
        int r = j >> 7;
        pF[j] = __float2bfloat16(r < 2000 ? acc[(size_t)(1000 + r) * 128 + (j & 127)] : 0.f);
    }
}

// ================================================================ launch
extern "C" void kernel_launch(void* const* d_in, const int* in_sizes, int n_in,
                              void* d_out, int out_size, void* d_ws, size_t ws_size,
                              hipStream_t stream)
{
    const float* A     = (const float*)d_in[0];
    const float* DTI   = (const float*)d_in[1];
    const float* drugS = (const float*)d_in[2];
    const float* protS = (const float*)d_in[3];
    const float* w0a   = (const float*)d_in[4];
    const float* w0b   = (const float*)d_in[5];
    const float* w1g   = (const float*)d_in[6];
    const float* ap    = (const float*)d_in[7];
    const float* wd1 = (const float*)d_in[10]; const float* bd1 = (const float*)d_in[11];
    const float* wd2 = (const float*)d_in[12]; const float* bd2 = (const float*)d_in[13];
    const float* wd3 = (const float*)d_in[14]; const float* bd3 = (const float*)d_in[15];
    const float* wp1 = (const float*)d_in[16]; const float* bp1 = (const float*)d_in[17];
    const float* wp2 = (const float*)d_in[18]; const float* bp2 = (const float*)d_in[19];
    const float* wp3 = (const float*)d_in[20]; const float* bp3 = (const float*)d_in[21];
    float* out = (float*)d_out;

    const size_t SQ_BF = (size_t)NPAD * NPAD * 2;   // 18,874,368
    char* p = (char*)d_ws;
    auto alloc = [&](size_t sz) { char* r = p; p += (sz + 255) & ~(size_t)255; return r; };
    __hip_bfloat16* sdti = (__hip_bfloat16*)alloc(SQ_BF);
    __hip_bfloat16* a0c[2], *b0c[2], *g1c[2];
    for (int c = 0; c < 2; ++c) {
        a0c[c] = (__hip_bfloat16*)alloc(SQ_BF);
        b0c[c] = (__hip_bfloat16*)alloc(SQ_BF);   // becomes S_c after gemm-adj
        g1c[c] = (__hip_bfloat16*)alloc(SQ_BF);
    }
    __hip_bfloat16* HnB  = (__hip_bfloat16*)alloc(SQ_BF);
    __hip_bfloat16* part = (__hip_bfloat16*)alloc((size_t)16 * 393216 * 2);
    float* cspart = (float*)alloc((size_t)4 * 24 * NPAD * 4);
    float* v4     = (float*)alloc((size_t)4 * NPAD * 4);
    float* dinv   = (float*)alloc((size_t)NPAD * 4);
    float* rsv    = (float*)alloc((size_t)NPAD * 4);
    float* degv   = (float*)alloc((size_t)NPAD * 4);
    float* fa   = (float*)alloc((size_t)NPAD * 128 * 4);
    float* fb   = (float*)alloc((size_t)NPAD * 128 * 4);
    float* conv = (float*)alloc((size_t)NPAD * 128 * 4);
    __hip_bfloat16* XTF = (__hip_bfloat16*)alloc((size_t)128 * NPAD * 2);
    __hip_bfloat16* XT2 = (__hip_bfloat16*)alloc((size_t)128 * NPAD * 2);
    __hip_bfloat16* dF = (__hip_bfloat16*)alloc((size_t)1024 * 128 * 2);
    __hip_bfloat16* pF = (__hip_bfloat16*)alloc((size_t)2048 * 128 * 2);
    if ((size_t)(p - (char*)d_ws) > ws_size) return;  // fail loud if ws too small

    // ---- MLPs: feature -> fb
    mlp_layer2<<<375, 256, 0, stream>>>(drugS, protS, wd1, bd1, wp1, bp1, fb);
    mlp_layer2<<<375, 256, 0, stream>>>(fb, fb + 1000 * 128, wd2, bd2, wp2, bp2, fa);
    mlp_layer2<<<375, 256, 0, stream>>>(fa, fa + 1000 * 128, wd3, bd3, wp3, bp3, fb);
    transpose_feat<<<dim3(96, 4), 256, 0, stream>>>(fb, 3000, XTF);

    // ---- gtconv: both channels in one pass over A
    gtconv2<<<dim3(24, 192), 256, 0, stream>>>(A, w0a, w0b, w1g,
        a0c[0], b0c[0], g1c[0], a0c[1], b0c[1], g1c[1]);
    // column sums (= row sums of b0/g1) for degree matvecs
    colsum4<<<dim3(2, 24, 4), 256, 0, stream>>>(b0c[0], g1c[0], b0c[1], g1c[1], cspart);
    colsum_fin<<<12, 256, 0, stream>>>(cspart, v4);

    // ---- DTI path
    rowdeg_f32<<<NPAD, 256, 0, stream>>>(DTI, degv);
    scale_cast_f32<<<dim3(3, NPAD), 256, 0, stream>>>(DTI, 3000, 3000, degv, sdti);
    gemm_bt<4><<<dim3(1, 24, 16), 256, 0, stream>>>(sdti, XTF, part, nullptr, 192, NPAD, NPAD, 128, 393216, 0, 0);
    reduce_trans<<<dim3(96, 4), 256, 0, stream>>>(part, XT2);
    gemm_bt<4><<<dim3(1, 24, 16), 256, 0, stream>>>(sdti, XT2, part, nullptr, 192, NPAD, NPAD, 128, 393216, 0, 0);
    reduce_att<1><<<1500, 256, 0, stream>>>(part, ap, 0, conv);

    // ---- per GT channel
    for (int c = 0; c < 2; ++c) {
        // deg(H) = a0 . rowsum(b0) + 1  -> dinv
        matvec_deg<0><<<NPAD, 256, 0, stream>>>(a0c[c], v4 + (size_t)(2 * c) * NPAD, dinv);
        // Hn = D^-1 (a0@b0 + I)  (bf16, fused epilogue)
        gemm_bt<2><<<dim3(24, 24, 1), 256, 0, stream>>>(a0c[c], b0c[c], HnB, dinv, NPAD, NPAD, NPAD, NPAD, 0, 0, 0);
        // deg2 = Hn . rowsum(g1) + 2 -> rs
        matvec_deg<1><<<NPAD, 256, 0, stream>>>(HnB, v4 + (size_t)(2 * c + 1) * NPAD, rsv);
        // S = D2^-1/2 (Hn@g1 + 2I) D2^-1/2  (bf16, fused epilogue; into b0 buffer)
        gemm_bt<3><<<dim3(24, 24, 1), 256, 0, stream>>>(HnB, g1c[c], b0c[c], rsv, NPAD, NPAD, NPAD, NPAD, 0, 0, 0);
        // two SGC hops
        gemm_bt<4><<<dim3(1, 24, 16), 256, 0, stream>>>(b0c[c], XTF, part, nullptr, 192, NPAD, NPAD, 128, 393216, 0, 0);
        reduce_trans<<<dim3(96, 4), 256, 0, stream>>>(part, XT2);
        gemm_bt<4><<<dim3(1, 24, 16), 256, 0, stream>>>(b0c[c], XT2, part, nullptr, 192, NPAD, NPAD, 128, 393216, 0, 0);
        reduce_att<0><<<1500, 256, 0, stream>>>(part, ap, c + 1, conv);
    }

    // ---- final: sigmoid(drug @ prot^T)
    cast_split<<<1536, 256, 0, stream>>>(conv, dF, pF);
    gemm_bt<1><<<dim3(16, 8, 1), 256, 0, stream>>>(dF, pF, out, nullptr, 128, 128, 128, 2000, 0, 1000, 2000);
}

// Round 6
// 411.528 us; speedup vs baseline: 2.1930x; 1.4703x over previous
//
#include <hip/hip_runtime.h>
#include <hip/hip_bf16.h>

typedef __attribute__((ext_vector_type(8))) __bf16 bf16x8;
typedef __attribute__((ext_vector_type(4))) float floatx4;

#define NVALID 3000
#define NPAD   3072
#define FEA    128
#define ZSPLIT 8
#define KCHUNK 384
#define PSTRIDE 393216   // NPAD*128

// async global->LDS, 16B per lane
__device__ __forceinline__ void gload16(const void* g, void* l) {
    __builtin_amdgcn_global_load_lds(
        (const __attribute__((address_space(1))) void*)g,
        (__attribute__((address_space(3))) void*)l,
        16, 0, 0);
}

__device__ __forceinline__ float b2f(__hip_bfloat16 h) { return __bfloat162float(h); }

// ---------------------------------------------------------------- MLP layer (drug+prot in one launch)
__global__ __launch_bounds__(256) void mlp_layer2(
    const float* __restrict__ Xd, const float* __restrict__ Xp,
    const float* __restrict__ Wd, const float* __restrict__ bd,
    const float* __restrict__ Wp, const float* __restrict__ bp,
    float* __restrict__ Y)
{
    const bool isP = blockIdx.x >= 125;
    const float* X = isP ? Xp : Xd;
    const float* W = isP ? Wp : Wd;
    const float* b = isP ? bp : bd;
    const int m0loc = (isP ? (blockIdx.x - 125) : blockIdx.x) * 8;
    const int m0out = blockIdx.x * 8;

    __shared__ float Xs[8][128];
    const int t = threadIdx.x;
    for (int s2 = t; s2 < 1024; s2 += 256) {
        int r = s2 >> 7, ii = s2 & 127;
        Xs[r][ii] = X[(size_t)(m0loc + r) * 128 + ii];
    }
    __syncthreads();
    const int o = t & 127, rh = t >> 7;
    float a0 = 0.f, a1 = 0.f, a2 = 0.f, a3 = 0.f;
    const float* wrow = W + (size_t)o * 128;
    for (int i = 0; i < 128; ++i) {
        float w = wrow[i];
        a0 += Xs[rh + 0][i] * w;
        a1 += Xs[rh + 2][i] * w;
        a2 += Xs[rh + 4][i] * w;
        a3 += Xs[rh + 6][i] * w;
    }
    const float bo = b[o];
    Y[(size_t)(m0out + rh + 0) * 128 + o] = fmaxf(a0 + bo, 0.f);
    Y[(size_t)(m0out + rh + 2) * 128 + o] = fmaxf(a1 + bo, 0.f);
    Y[(size_t)(m0out + rh + 4) * 128 + o] = fmaxf(a2 + bo, 0.f);
    Y[(size_t)(m0out + rh + 6) * 128 + o] = fmaxf(a3 + bo, 0.f);
}

// ---------------------------------------------------------------- softmax5
__device__ __forceinline__ void softmax5(const float* __restrict__ w, float* s)
{
    float m = w[0];
    #pragma unroll
    for (int e = 1; e < 5; ++e) m = fmaxf(m, w[e]);
    float sum = 0.f;
    #pragma unroll
    for (int e = 0; e < 5; ++e) { s[e] = __expf(w[e] - m); sum += s[e]; }
    float r = 1.f / sum;
    #pragma unroll
    for (int e = 0; e < 5; ++e) s[e] *= r;
}

// ---------------------------------------------------------------- gtconv streaming (no LDS, 6 row-major outputs)
// grid dim3(3, NPAD), block 256; thread handles 4 consecutive cols of row i.
__global__ __launch_bounds__(256) void gtconv_stream(
    const float* __restrict__ A, const float* __restrict__ w0a,
    const float* __restrict__ w0b, const float* __restrict__ w1,
    __hip_bfloat16* __restrict__ a00, __hip_bfloat16* __restrict__ b00,
    __hip_bfloat16* __restrict__ g10,
    __hip_bfloat16* __restrict__ a01, __hip_bfloat16* __restrict__ b01,
    __hip_bfloat16* __restrict__ g11)
{
    float sa0[5], sb0[5], sg0[5], sa1[5], sb1[5], sg1[5];
    softmax5(w0a + 0, sa0); softmax5(w0b + 0, sb0); softmax5(w1 + 0, sg0);
    softmax5(w0a + 5, sa1); softmax5(w0b + 5, sb1); softmax5(w1 + 5, sg1);

    const int i  = blockIdx.y;
    const int j0 = blockIdx.x * 1024 + threadIdx.x * 4;
    float acc[6][4] = {};
    if (i < NVALID && j0 < NVALID) {
        const bool fast = (j0 + 3) < NVALID;
        #pragma unroll
        for (int e = 0; e < 5; ++e) {
            const float* Ae = A + (size_t)e * 9000000 + (size_t)i * 3000;
            float x[4];
            if (fast) {
                float4 v = *reinterpret_cast<const float4*>(Ae + j0);
                x[0] = v.x; x[1] = v.y; x[2] = v.z; x[3] = v.w;
            } else {
                #pragma unroll
                for (int u = 0; u < 4; ++u)
                    x[u] = (j0 + u < NVALID) ? Ae[j0 + u] : 0.f;
            }
            #pragma unroll
            for (int u = 0; u < 4; ++u) {
                acc[0][u] += sa0[e] * x[u];
                acc[1][u] += sb0[e] * x[u];
                acc[2][u] += sg0[e] * x[u];
                acc[3][u] += sa1[e] * x[u];
                acc[4][u] += sb1[e] * x[u];
                acc[5][u] += sg1[e] * x[u];
            }
        }
    }
    __hip_bfloat16* dsts[6] = { a00, b00, g10, a01, b01, g11 };
    const size_t base = (size_t)i * NPAD + j0;
    #pragma unroll
    for (int m = 0; m < 6; ++m) {
        __align__(8) __hip_bfloat16 h[4];
        #pragma unroll
        for (int u = 0; u < 4; ++u) h[u] = __float2bfloat16(acc[m][u]);
        *reinterpret_cast<uint2*>(&dsts[m][base]) = *reinterpret_cast<const uint2*>(h);
    }
}

// ---------------------------------------------------------------- row sums of the 4 (b0,g1) matrices
// grid dim3(NPAD, 4); out r1v[z*NPAD + i]
__global__ __launch_bounds__(256) void rowsum4(
    const __hip_bfloat16* __restrict__ M0, const __hip_bfloat16* __restrict__ M1,
    const __hip_bfloat16* __restrict__ M2, const __hip_bfloat16* __restrict__ M3,
    float* __restrict__ r1v)
{
    const __hip_bfloat16* M = (blockIdx.y == 0) ? M0 : (blockIdx.y == 1) ? M1
                            : (blockIdx.y == 2) ? M2 : M3;
    const size_t i = blockIdx.x;
    const int t = threadIdx.x;
    const __hip_bfloat16* row = M + i * NPAD;
    float s = 0.f;
    for (int k = t * 8; k < NPAD; k += 2048) {
        uint4 u = *reinterpret_cast<const uint4*>(&row[k]);   // 16B = 8 bf16
        const unsigned short* us = reinterpret_cast<const unsigned short*>(&u);
        #pragma unroll
        for (int e = 0; e < 8; ++e)
            s += __uint_as_float(((unsigned int)us[e]) << 16);
    }
    #pragma unroll
    for (int off = 32; off > 0; off >>= 1) s += __shfl_down(s, off);
    __shared__ float red[4];
    if ((t & 63) == 0) red[t >> 6] = s;
    __syncthreads();
    if (t == 0)
        r1v[(size_t)blockIdx.y * NPAD + i] = red[0] + red[1] + red[2] + red[3];
}

// ---------------------------------------------------------------- matvec (bf16 M, f32 v)
// MODE 0: out = M.v ; MODE 1: out = 1/(M.v+1) ; MODE 2: out = rsqrt(dinv[i]*(M.v+addv[i])+2)
template<int MODE>
__global__ __launch_bounds__(256) void matvec(
    const __hip_bfloat16* __restrict__ M, const float* __restrict__ v,
    const float* __restrict__ dinvv, const float* __restrict__ addv,
    float* __restrict__ outv)
{
    const size_t i = blockIdx.x;
    const int t = threadIdx.x;
    const __hip_bfloat16* row = M + i * NPAD;
    float s = 0.f;
    for (int k = t * 8; k < NPAD; k += 2048) {
        uint4 u = *reinterpret_cast<const uint4*>(&row[k]);   // 16B = 8 bf16
        const unsigned short* us = reinterpret_cast<const unsigned short*>(&u);
        #pragma unroll
        for (int e = 0; e < 8; ++e)
            s += __uint_as_float(((unsigned int)us[e]) << 16) * v[k + e];
    }
    #pragma unroll
    for (int off = 32; off > 0; off >>= 1) s += __shfl_down(s, off);
    __shared__ float red[4];
    if ((t & 63) == 0) red[t >> 6] = s;
    __syncthreads();
    if (t == 0) {
        float tot = red[0] + red[1] + red[2] + red[3];
        if (MODE == 0)      outv[i] = tot;
        else if (MODE == 1) outv[i] = 1.f / (tot + 1.f);
        else                outv[i] = rsqrtf(dinvv[i] * (tot + addv[i]) + 2.f);
    }
}

// ---------------------------------------------------------------- DTI degree (f32, float4)
__global__ __launch_bounds__(256) void rowdeg_f32(
    const float* __restrict__ src, float* __restrict__ outv)
{
    const int i = blockIdx.x, t = threadIdx.x;
    float s = 0.f;
    if (i < NVALID) {
        const float* row = src + (size_t)i * 3000;
        for (int j4 = t; j4 < 750; j4 += 256) {
            float4 v = *reinterpret_cast<const float4*>(row + j4 * 4);
            s += v.x + v.y + v.z + v.w;
        }
    }
    #pragma unroll
    for (int off = 32; off > 0; off >>= 1) s += __shfl_down(s, off);
    __shared__ float red[4];
    if ((t & 63) == 0) red[t >> 6] = s;
    __syncthreads();
    if (t == 0) {
        float tot = red[0] + red[1] + red[2] + red[3];
        outv[i] = rsqrtf(tot + 2.f);
    }
}

__global__ __launch_bounds__(256) void scale_cast_f32(
    const float* __restrict__ src, int lds_, int nvalid,
    const float* __restrict__ vec, __hip_bfloat16* __restrict__ dst)
{
    const int i = blockIdx.y;
    const int j0 = (blockIdx.x * 256 + threadIdx.x) * 4;
    const float vi = vec[i];
    float v[4];
    if (i < nvalid && j0 + 3 < nvalid) {
        float4 f = *reinterpret_cast<const float4*>(src + (size_t)i * lds_ + j0);
        v[0] = f.x; v[1] = f.y; v[2] = f.z; v[3] = f.w;
    } else {
        #pragma unroll
        for (int u = 0; u < 4; ++u) {
            int j = j0 + u;
            v[u] = (i < nvalid && j < nvalid) ? src[(size_t)i * lds_ + j] : 0.f;
        }
    }
    #pragma unroll
    for (int u = 0; u < 4; ++u) {
        int j = j0 + u;
        if (j == i && i < nvalid) v[u] += 2.f;
        v[u] *= vi * vec[j];
    }
    __align__(8) __hip_bfloat16 h[4];
    #pragma unroll
    for (int u = 0; u < 4; ++u) h[u] = __float2bfloat16(v[u]);
    *reinterpret_cast<uint2*>(&dst[(size_t)i * NPAD + j0]) =
        *reinterpret_cast<const uint2*>(h);
}

// ---------------------------------------------------------------- transpose feature (f32 -> bf16^T)
__global__ __launch_bounds__(256) void transpose_feat(
    const float* __restrict__ X, int nvalid, __hip_bfloat16* __restrict__ XT)
{
    __shared__ float Ts[32][33];
    const int k0 = blockIdx.x * 32, n0 = blockIdx.y * 32;
    const int t = threadIdx.x, tr = t >> 5, tc = t & 31;
    #pragma unroll
    for (int p = 0; p < 4; ++p) {
        int k = k0 + tr + p * 8;
        Ts[tr + p * 8][tc] = (k < nvalid) ? X[(size_t)k * 128 + n0 + tc] : 0.f;
    }
    __syncthreads();
    #pragma unroll
    for (int p = 0; p < 4; ++p) {
        int n = tr + p * 8;
        XT[(size_t)(n0 + n) * NPAD + k0 + tc] = __float2bfloat16(Ts[tc][n]);
    }
}

// ---------------------------------------------------------------- scale columns of XT by s[k] -> W0T
// grid dim3(2, 128), block 256; thread handles 8 consecutive k of row f.
__global__ __launch_bounds__(256) void scale_colsT(
    const __hip_bfloat16* __restrict__ XT, const float* __restrict__ s,
    __hip_bfloat16* __restrict__ W0T)
{
    const int f = blockIdx.y;
    const int k0 = (blockIdx.x * 256 + threadIdx.x) * 8;
    if (k0 >= NPAD) return;
    uint4 u = *reinterpret_cast<const uint4*>(&XT[(size_t)f * NPAD + k0]);
    const unsigned short* us = reinterpret_cast<const unsigned short*>(&u);
    __align__(16) __hip_bfloat16 h[8];
    #pragma unroll
    for (int e = 0; e < 8; ++e) {
        float x = __uint_as_float(((unsigned int)us[e]) << 16);
        h[e] = __float2bfloat16(x * s[k0 + e]);
    }
    *reinterpret_cast<uint4*>(&W0T[(size_t)f * NPAD + k0]) =
        *reinterpret_cast<const uint4*>(h);
}

// ---------------------------------------------------------------- GEMM (B^T layout), m97 structure
// EPI 0: f32 plain store at z-offset (K-split partials). EPI 1: sigmoid + bounds.
template<int EPI>
__global__ __launch_bounds__(256, 3) void gemm_bt(
    const __hip_bfloat16* __restrict__ A, const __hip_bfloat16* __restrict__ BT,
    void* __restrict__ Cv,
    int Kchunk, int lda, int ldb, int ldc,
    size_t zstride, int Mvalid, int Nvalid)
{
    __shared__ __align__(16) __hip_bfloat16 As[128 * 32];
    __shared__ __align__(16) __hip_bfloat16 Bs[128 * 32];
    const int t = threadIdx.x;
    const int lane = t & 63;
    const int w = t >> 6;
    const int wm = w >> 1, wn = w & 1;
    const int tm = blockIdx.y, tn = blockIdx.x;
    const int kbeg = blockIdx.z * Kchunk;

    const int srow = lane >> 2;
    const int skg  = (lane & 3) * 8;
    const __hip_bfloat16* Ag = A  + (size_t)(tm * 128 + w * 32 + srow) * lda + skg;
    const __hip_bfloat16* Bg = BT + (size_t)(tn * 128 + w * 32 + srow) * ldb + skg;
    __hip_bfloat16* Al0 = &As[w * 1024];
    __hip_bfloat16* Al1 = &As[w * 1024 + 512];
    __hip_bfloat16* Bl0 = &Bs[w * 1024];
    __hip_bfloat16* Bl1 = &Bs[w * 1024 + 512];

    floatx4 acc[4][4] = {};

    for (int k0 = kbeg; k0 < kbeg + Kchunk; k0 += 32) {
        __syncthreads();
        gload16(Ag + k0,            Al0);
        gload16(Ag + 16 * lda + k0, Al1);
        gload16(Bg + k0,            Bl0);
        gload16(Bg + 16 * ldb + k0, Bl1);
        __syncthreads();

        bf16x8 af[4], bfv[4];
        const int koff = (lane >> 4) * 8;
        #pragma unroll
        for (int mi = 0; mi < 4; ++mi)
            af[mi] = *reinterpret_cast<const bf16x8*>(
                &As[(wm * 64 + mi * 16 + (lane & 15)) * 32 + koff]);
        #pragma unroll
        for (int ni = 0; ni < 4; ++ni)
            bfv[ni] = *reinterpret_cast<const bf16x8*>(
                &Bs[(wn * 64 + ni * 16 + (lane & 15)) * 32 + koff]);
        #pragma unroll
        for (int mi = 0; mi < 4; ++mi)
            #pragma unroll
            for (int ni = 0; ni < 4; ++ni)
                acc[mi][ni] = __builtin_amdgcn_mfma_f32_16x16x32_bf16(
                    af[mi], bfv[ni], acc[mi][ni], 0, 0, 0);
    }

    const int r0 = tm * 128 + wm * 64 + ((lane >> 4) << 2);
    const int c0 = tn * 128 + wn * 64 + (lane & 15);
    #pragma unroll
    for (int mi = 0; mi < 4; ++mi) {
        #pragma unroll
        for (int ni = 0; ni < 4; ++ni) {
            const int col = c0 + ni * 16;
            #pragma unroll
            for (int r = 0; r < 4; ++r) {
                const int row = r0 + mi * 16 + r;
                float v = acc[mi][ni][r];
                if (EPI == 0) {
                    float* C = (float*)Cv + (size_t)blockIdx.z * zstride;
                    C[(size_t)row * ldc + col] = v;
                } else {
                    float* C = (float*)Cv;
                    if (row < Mvalid && col < Nvalid)
                        C[(size_t)row * ldc + col] = 1.f / (1.f + __expf(-v));
                }
            }
        }
    }
}

// ---------------------------------------------------------------- K-split reduce + transpose (f32 partials)
// RM=1: also write row-major bf16 copy of the reduced panel.
template<int RM>
__global__ __launch_bounds__(256) void reduce_trans(
    const float* __restrict__ Pp, __hip_bfloat16* __restrict__ XT,
    __hip_bfloat16* __restrict__ Rm)
{
    __shared__ float Ts[32][33];
    const int k0 = blockIdx.x * 32, n0 = blockIdx.y * 32;
    const int t = threadIdx.x, tr = t >> 5, tc = t & 31;
    #pragma unroll
    for (int p = 0; p < 4; ++p) {
        int i = k0 + tr + p * 8;
        float s = 0.f;
        #pragma unroll
        for (int z = 0; z < ZSPLIT; ++z)
            s += Pp[(size_t)z * PSTRIDE + (size_t)i * 128 + n0 + tc];
        Ts[tr + p * 8][tc] = s;
        if (RM) Rm[(size_t)i * 128 + n0 + tc] = __float2bfloat16(s);
    }
    __syncthreads();
    #pragma unroll
    for (int p = 0; p < 4; ++p) {
        int n = tr + p * 8;
        XT[(size_t)(n0 + n) * NPAD + k0 + tc] = __float2bfloat16(Ts[tc][n]);
    }
}

// ---------------------------------------------------------------- DTI hop2: reduce + attention write
__global__ __launch_bounds__(256) void reduce_att_f32(
    const float* __restrict__ Pp, const float* __restrict__ ap,
    float* __restrict__ conv)
{
    const int idx = blockIdx.x * 256 + threadIdx.x;  // grid 1500 -> 3000*128
    float s = 0.f;
    #pragma unroll
    for (int z = 0; z < ZSPLIT; ++z)
        s += Pp[(size_t)z * PSTRIDE + idx];
    float a0 = ap[0], a1 = ap[1], a2 = ap[2];
    float m = fmaxf(a0, fmaxf(a1, a2));
    float e0 = __expf(a0 - m), e1 = __expf(a1 - m), e2 = __expf(a2 - m);
    conv[idx] = (e0 / (e0 + e1 + e2)) * s;
}

// ---------------------------------------------------------------- channel hop1 combine
// out1 = s*dinv*(V+Z) + 2*s^2*X ; store W0' = s*out1 in both layouts
__global__ __launch_bounds__(256) void combine_mid(
    const float* __restrict__ Vp, const __hip_bfloat16* __restrict__ Zrm,
    const float* __restrict__ X, const float* __restrict__ sv,
    const float* __restrict__ dv,
    __hip_bfloat16* __restrict__ WpT, __hip_bfloat16* __restrict__ Wprm)
{
    __shared__ float Ts[32][33];
    const int k0 = blockIdx.x * 32, n0 = blockIdx.y * 32;
    const int t = threadIdx.x, tr = t >> 5, tc = t & 31;
    #pragma unroll
    for (int p = 0; p < 4; ++p) {
        int i = k0 + tr + p * 8;
        int f = n0 + tc;
        float vsum = b2f(Zrm[(size_t)i * 128 + f]);
        #pragma unroll
        for (int z = 0; z < ZSPLIT; ++z)
            vsum += Vp[(size_t)z * PSTRIDE + (size_t)i * 128 + f];
        float x  = (i < NVALID) ? X[(size_t)i * 128 + f] : 0.f;
        float si = sv[i];
        float out1 = si * dv[i] * vsum + 2.f * si * si * x;
        float wv = si * out1;
        Ts[tr + p * 8][tc] = wv;
        Wprm[(size_t)i * 128 + f] = __float2bfloat16(wv);
    }
    __syncthreads();
    #pragma unroll
    for (int p = 0; p < 4; ++p) {
        int n = tr + p * 8;
        WpT[(size_t)(n0 + n) * NPAD + k0 + tc] = __float2bfloat16(Ts[tc][n]);
    }
}

// ---------------------------------------------------------------- channel hop2 combine + attention accumulate
// final = s*dinv*(V+Z2) + 2*s*Wprm ; conv += att[kk]*final
__global__ __launch_bounds__(256) void combine_att(
    const float* __restrict__ Vp, const __hip_bfloat16* __restrict__ Zrm,
    const __hip_bfloat16* __restrict__ Wprm, const float* __restrict__ sv,
    const float* __restrict__ dv, const float* __restrict__ ap, int kk,
    float* __restrict__ conv)
{
    const int idx = blockIdx.x * 256 + threadIdx.x;  // grid 1500 -> 3000*128
    const int i = idx >> 7;
    float vsum = b2f(Zrm[idx]);
    #pragma unroll
    for (int z = 0; z < ZSPLIT; ++z)
        vsum += Vp[(size_t)z * PSTRIDE + idx];
    float si = sv[i];
    float o = si * dv[i] * vsum + 2.f * si * b2f(Wprm[idx]);
    float a0 = ap[0], a1 = ap[1], a2 = ap[2];
    float m = fmaxf(a0, fmaxf(a1, a2));
    float e0 = __expf(a0 - m), e1 = __expf(a1 - m), e2 = __expf(a2 - m);
    float att = ((kk == 1) ? e1 : e2) / (e0 + e1 + e2);
    conv[idx] += att * o;
}

// ---------------------------------------------------------------- final split+cast
__global__ __launch_bounds__(256) void cast_split(
    const float* __restrict__ acc, __hip_bfloat16* __restrict__ dF,
    __hip_bfloat16* __restrict__ pF)
{
    const int idx = blockIdx.x * 256 + threadIdx.x;
    if (idx < 1024 * 128) {
        int r = idx >> 7;
        dF[idx] = __float2bfloat16(r < 1000 ? acc[idx] : 0.f);
    } else {
        int j = idx - 1024 * 128;
        int r = j >> 7;
        pF[j] = __float2bfloat16(r < 2000 ? acc[(size_t)(1000 + r) * 128 + (j & 127)] : 0.f);
    }
}

// ================================================================ launch
extern "C" void kernel_launch(void* const* d_in, const int* in_sizes, int n_in,
                              void* d_out, int out_size, void* d_ws, size_t ws_size,
                              hipStream_t stream)
{
    const float* A     = (const float*)d_in[0];
    const float* DTI   = (const float*)d_in[1];
    const float* drugS = (const float*)d_in[2];
    const float* protS = (const float*)d_in[3];
    const float* w0a   = (const float*)d_in[4];
    const float* w0b   = (const float*)d_in[5];
    const float* w1g   = (const float*)d_in[6];
    const float* ap    = (const float*)d_in[7];
    const float* wd1 = (const float*)d_in[10]; const float* bd1 = (const float*)d_in[11];
    const float* wd2 = (const float*)d_in[12]; const float* bd2 = (const float*)d_in[13];
    const float* wd3 = (const float*)d_in[14]; const float* bd3 = (const float*)d_in[15];
    const float* wp1 = (const float*)d_in[16]; const float* bp1 = (const float*)d_in[17];
    const float* wp2 = (const float*)d_in[18]; const float* bp2 = (const float*)d_in[19];
    const float* wp3 = (const float*)d_in[20]; const float* bp3 = (const float*)d_in[21];
    float* out = (float*)d_out;

    const size_t SQ_BF = (size_t)NPAD * NPAD * 2;     // 18,874,368
    const size_t PAN_BF = (size_t)128 * NPAD * 2;     // 786,432  (both layouts same size)
    char* p = (char*)d_ws;
    auto alloc = [&](size_t sz) { char* r = p; p += (sz + 255) & ~(size_t)255; return r; };
    __hip_bfloat16* sdti = (__hip_bfloat16*)alloc(SQ_BF);
    __hip_bfloat16* a0c[2], *b0c[2], *g1c[2];
    for (int c = 0; c < 2; ++c) {
        a0c[c] = (__hip_bfloat16*)alloc(SQ_BF);
        b0c[c] = (__hip_bfloat16*)alloc(SQ_BF);
        g1c[c] = (__hip_bfloat16*)alloc(SQ_BF);
    }
    float* part = (float*)alloc((size_t)ZSPLIT * PSTRIDE * 4);   // 12.6 MB f32 partials
    float* r1v  = (float*)alloc((size_t)4 * NPAD * 4);           // rowsums: b0c0,g1c0,b0c1,g1c1
    float* dinv = (float*)alloc((size_t)NPAD * 4);
    float* mv1  = (float*)alloc((size_t)NPAD * 4);
    float* rsv  = (float*)alloc((size_t)NPAD * 4);
    float* degv = (float*)alloc((size_t)NPAD * 4);
    float* fa   = (float*)alloc((size_t)NPAD * 128 * 4);
    float* fb   = (float*)alloc((size_t)NPAD * 128 * 4);
    float* conv = (float*)alloc((size_t)NPAD * 128 * 4);
    __hip_bfloat16* XTF  = (__hip_bfloat16*)alloc(PAN_BF);
    __hip_bfloat16* XT2  = (__hip_bfloat16*)alloc(PAN_BF);
    __hip_bfloat16* W0T  = (__hip_bfloat16*)alloc(PAN_BF);
    __hip_bfloat16* ZT   = (__hip_bfloat16*)alloc(PAN_BF);
    __hip_bfloat16* Zrm  = (__hip_bfloat16*)alloc(PAN_BF);
    __hip_bfloat16* UT   = (__hip_bfloat16*)alloc(PAN_BF);
    __hip_bfloat16* WpT  = (__hip_bfloat16*)alloc(PAN_BF);
    __hip_bfloat16* Wprm = (__hip_bfloat16*)alloc(PAN_BF);
    __hip_bfloat16* dF = (__hip_bfloat16*)alloc((size_t)1024 * 128 * 2);
    __hip_bfloat16* pF = (__hip_bfloat16*)alloc((size_t)2048 * 128 * 2);
    if ((size_t)(p - (char*)d_ws) > ws_size) return;  // fail loud if ws too small

    // ---- MLPs: feature -> fb
    mlp_layer2<<<375, 256, 0, stream>>>(drugS, protS, wd1, bd1, wp1, bp1, fb);
    mlp_layer2<<<375, 256, 0, stream>>>(fb, fb + 1000 * 128, wd2, bd2, wp2, bp2, fa);
    mlp_layer2<<<375, 256, 0, stream>>>(fa, fa + 1000 * 128, wd3, bd3, wp3, bp3, fb);
    transpose_feat<<<dim3(96, 4), 256, 0, stream>>>(fb, 3000, XTF);

    // ---- gtconv: streaming, all 6 outputs row-major
    gtconv_stream<<<dim3(3, NPAD), 256, 0, stream>>>(A, w0a, w0b, w1g,
        a0c[0], b0c[0], g1c[0], a0c[1], b0c[1], g1c[1]);
    rowsum4<<<dim3(NPAD, 4), 256, 0, stream>>>(b0c[0], g1c[0], b0c[1], g1c[1], r1v);

    // ---- DTI path (S_DTI materialized; two plain hops)
    rowdeg_f32<<<NPAD, 256, 0, stream>>>(DTI, degv);
    scale_cast_f32<<<dim3(3, NPAD), 256, 0, stream>>>(DTI, 3000, 3000, degv, sdti);
    gemm_bt<0><<<dim3(1, 24, ZSPLIT), 256, 0, stream>>>(sdti, XTF, part, KCHUNK, NPAD, NPAD, 128, PSTRIDE, 0, 0);
    reduce_trans<0><<<dim3(96, 4), 256, 0, stream>>>(part, XT2, nullptr);
    gemm_bt<0><<<dim3(1, 24, ZSPLIT), 256, 0, stream>>>(sdti, XT2, part, KCHUNK, NPAD, NPAD, 128, PSTRIDE, 0, 0);
    reduce_att_f32<<<1500, 256, 0, stream>>>(part, ap, conv);

    // ---- per GT channel (factored hops: S@Y = s∘(dinv∘(a0@(b0@(g1@W0)) + g1@W0) + 2W0), W0 = s∘Y)
    for (int c = 0; c < 2; ++c) {
        const float* r1b = r1v + (size_t)(2 * c) * NPAD;
        const float* r1g = r1v + (size_t)(2 * c + 1) * NPAD;
        // degrees: dinv = 1/(a0@r1b + 1); rsv = rsqrt(dinv*(a0@(b0@r1g) + r1g) + 2)
        matvec<1><<<NPAD, 256, 0, stream>>>(a0c[c], r1b, nullptr, nullptr, dinv);
        matvec<0><<<NPAD, 256, 0, stream>>>(b0c[c], r1g, nullptr, nullptr, mv1);
        matvec<2><<<NPAD, 256, 0, stream>>>(a0c[c], mv1, dinv, r1g, rsv);
        // hop 1: W0T = rsv∘XTF
        scale_colsT<<<dim3(2, 128), 256, 0, stream>>>(XTF, rsv, W0T);
        gemm_bt<0><<<dim3(1, 24, ZSPLIT), 256, 0, stream>>>(g1c[c], W0T, part, KCHUNK, NPAD, NPAD, 128, PSTRIDE, 0, 0);
        reduce_trans<1><<<dim3(96, 4), 256, 0, stream>>>(part, ZT, Zrm);
        gemm_bt<0><<<dim3(1, 24, ZSPLIT), 256, 0, stream>>>(b0c[c], ZT, part, KCHUNK, NPAD, NPAD, 128, PSTRIDE, 0, 0);
        reduce_trans<0><<<dim3(96, 4), 256, 0, stream>>>(part, UT, nullptr);
        gemm_bt<0><<<dim3(1, 24, ZSPLIT), 256, 0, stream>>>(a0c[c], UT, part, KCHUNK, NPAD, NPAD, 128, PSTRIDE, 0, 0);
        combine_mid<<<dim3(96, 4), 256, 0, stream>>>(part, Zrm, fb, rsv, dinv, WpT, Wprm);
        // hop 2 (input already scaled: W0' = WpT/Wprm)
        gemm_bt<0><<<dim3(1, 24, ZSPLIT), 256, 0, stream>>>(g1c[c], WpT, part, KCHUNK, NPAD, NPAD, 128, PSTRIDE, 0, 0);
        reduce_trans<1><<<dim3(96, 4), 256, 0, stream>>>(part, ZT, Zrm);
        gemm_bt<0><<<dim3(1, 24, ZSPLIT), 256, 0, stream>>>(b0c[c], ZT, part, KCHUNK, NPAD, NPAD, 128, PSTRIDE, 0, 0);
        reduce_trans<0><<<dim3(96, 4), 256, 0, stream>>>(part, UT, nullptr);
        gemm_bt<0><<<dim3(1, 24, ZSPLIT), 256, 0, stream>>>(a0c[c], UT, part, KCHUNK, NPAD, NPAD, 128, PSTRIDE, 0, 0);
        combine_att<<<1500, 256, 0, stream>>>(part, Zrm, Wprm, rsv, dinv, ap, c + 1, conv);
    }

    // ---- final: sigmoid(drug @ prot^T)
    cast_split<<<1536, 256, 0, stream>>>(conv, dF, pF);
    gemm_bt<1><<<dim3(16, 8, 1), 256, 0, stream>>>(dF, pF, out, 128, 128, 128, 2000, 0, 1000, 2000);
}

// Round 7
// 288.684 us; speedup vs baseline: 3.1262x; 1.4255x over previous
//
#include <hip/hip_runtime.h>
#include <hip/hip_bf16.h>

typedef __attribute__((ext_vector_type(8))) __bf16 bf16x8;
typedef __attribute__((ext_vector_type(4))) float floatx4;

#define NVALID 3000
#define NPAD   3072
#define FEA    128
#define ZSPLIT 8
#define KCHUNK 384
#define PSTRIDE 393216   // NPAD*128
#define SLOT   ((size_t)ZSPLIT * PSTRIDE)

// async global->LDS, 16B per lane
__device__ __forceinline__ void gload16(const void* g, void* l) {
    __builtin_amdgcn_global_load_lds(
        (const __attribute__((address_space(1))) void*)g,
        (__attribute__((address_space(3))) void*)l,
        16, 0, 0);
}

__device__ __forceinline__ float b2f(__hip_bfloat16 h) { return __bfloat162float(h); }

// ---------------------------------------------------------------- fused 3-layer MLP (row-independent)
__global__ __launch_bounds__(256) void mlp_fused(
    const float* __restrict__ Xd, const float* __restrict__ Xp,
    const float* __restrict__ Wd1, const float* __restrict__ bd1,
    const float* __restrict__ Wd2, const float* __restrict__ bd2,
    const float* __restrict__ Wd3, const float* __restrict__ bd3,
    const float* __restrict__ Wp1, const float* __restrict__ bp1,
    const float* __restrict__ Wp2, const float* __restrict__ bp2,
    const float* __restrict__ Wp3, const float* __restrict__ bp3,
    float* __restrict__ Y)
{
    const bool isP = blockIdx.x >= 125;
    const float* X  = isP ? Xp : Xd;
    const float* W1 = isP ? Wp1 : Wd1; const float* b1 = isP ? bp1 : bd1;
    const float* W2 = isP ? Wp2 : Wd2; const float* b2 = isP ? bp2 : bd2;
    const float* W3 = isP ? Wp3 : Wd3; const float* b3 = isP ? bp3 : bd3;
    const int m0loc = (isP ? (blockIdx.x - 125) : blockIdx.x) * 8;
    const int m0out = blockIdx.x * 8;

    __shared__ float S0[8][128], S1[8][128];
    const int t = threadIdx.x;
    for (int s2 = t; s2 < 1024; s2 += 256) {
        int r = s2 >> 7, ii = s2 & 127;
        S0[r][ii] = X[(size_t)(m0loc + r) * 128 + ii];
    }
    __syncthreads();
    const int o = t & 127, rh = t >> 7;

    // layer1: S0 -> S1
    {
        float a0 = 0.f, a1 = 0.f, a2 = 0.f, a3 = 0.f;
        const float* wr = W1 + (size_t)o * 128;
        for (int i = 0; i < 128; ++i) {
            float w = wr[i];
            a0 += S0[rh + 0][i] * w; a1 += S0[rh + 2][i] * w;
            a2 += S0[rh + 4][i] * w; a3 += S0[rh + 6][i] * w;
        }
        float bo = b1[o];
        S1[rh + 0][o] = fmaxf(a0 + bo, 0.f);
        S1[rh + 2][o] = fmaxf(a1 + bo, 0.f);
        S1[rh + 4][o] = fmaxf(a2 + bo, 0.f);
        S1[rh + 6][o] = fmaxf(a3 + bo, 0.f);
    }
    __syncthreads();
    // layer2: S1 -> S0
    {
        float a0 = 0.f, a1 = 0.f, a2 = 0.f, a3 = 0.f;
        const float* wr = W2 + (size_t)o * 128;
        for (int i = 0; i < 128; ++i) {
            float w = wr[i];
            a0 += S1[rh + 0][i] * w; a1 += S1[rh + 2][i] * w;
            a2 += S1[rh + 4][i] * w; a3 += S1[rh + 6][i] * w;
        }
        float bo = b2[o];
        S0[rh + 0][o] = fmaxf(a0 + bo, 0.f);
        S0[rh + 2][o] = fmaxf(a1 + bo, 0.f);
        S0[rh + 4][o] = fmaxf(a2 + bo, 0.f);
        S0[rh + 6][o] = fmaxf(a3 + bo, 0.f);
    }
    __syncthreads();
    // layer3: S0 -> global
    {
        float a0 = 0.f, a1 = 0.f, a2 = 0.f, a3 = 0.f;
        const float* wr = W3 + (size_t)o * 128;
        for (int i = 0; i < 128; ++i) {
            float w = wr[i];
            a0 += S0[rh + 0][i] * w; a1 += S0[rh + 2][i] * w;
            a2 += S0[rh + 4][i] * w; a3 += S0[rh + 6][i] * w;
        }
        float bo = b3[o];
        Y[(size_t)(m0out + rh + 0) * 128 + o] = fmaxf(a0 + bo, 0.f);
        Y[(size_t)(m0out + rh + 2) * 128 + o] = fmaxf(a1 + bo, 0.f);
        Y[(size_t)(m0out + rh + 4) * 128 + o] = fmaxf(a2 + bo, 0.f);
        Y[(size_t)(m0out + rh + 6) * 128 + o] = fmaxf(a3 + bo, 0.f);
    }
}

// ---------------------------------------------------------------- softmax5
__device__ __forceinline__ void softmax5(const float* __restrict__ w, float* s)
{
    float m = w[0];
    #pragma unroll
    for (int e = 1; e < 5; ++e) m = fmaxf(m, w[e]);
    float sum = 0.f;
    #pragma unroll
    for (int e = 0; e < 5; ++e) { s[e] = __expf(w[e] - m); sum += s[e]; }
    float r = 1.f / sum;
    #pragma unroll
    for (int e = 0; e < 5; ++e) s[e] *= r;
}

// ---------------------------------------------------------------- gtconv streaming (no LDS, 6 row-major outputs)
__global__ __launch_bounds__(256) void gtconv_stream(
    const float* __restrict__ A, const float* __restrict__ w0a,
    const float* __restrict__ w0b, const float* __restrict__ w1,
    __hip_bfloat16* __restrict__ a00, __hip_bfloat16* __restrict__ b00,
    __hip_bfloat16* __restrict__ g10,
    __hip_bfloat16* __restrict__ a01, __hip_bfloat16* __restrict__ b01,
    __hip_bfloat16* __restrict__ g11)
{
    float sa0[5], sb0[5], sg0[5], sa1[5], sb1[5], sg1[5];
    softmax5(w0a + 0, sa0); softmax5(w0b + 0, sb0); softmax5(w1 + 0, sg0);
    softmax5(w0a + 5, sa1); softmax5(w0b + 5, sb1); softmax5(w1 + 5, sg1);

    const int i  = blockIdx.y;
    const int j0 = blockIdx.x * 1024 + threadIdx.x * 4;
    float acc[6][4] = {};
    if (i < NVALID && j0 < NVALID) {
        const bool fast = (j0 + 3) < NVALID;
        #pragma unroll
        for (int e = 0; e < 5; ++e) {
            const float* Ae = A + (size_t)e * 9000000 + (size_t)i * 3000;
            float x[4];
            if (fast) {
                float4 v = *reinterpret_cast<const float4*>(Ae + j0);
                x[0] = v.x; x[1] = v.y; x[2] = v.z; x[3] = v.w;
            } else {
                #pragma unroll
                for (int u = 0; u < 4; ++u)
                    x[u] = (j0 + u < NVALID) ? Ae[j0 + u] : 0.f;
            }
            #pragma unroll
            for (int u = 0; u < 4; ++u) {
                acc[0][u] += sa0[e] * x[u];
                acc[1][u] += sb0[e] * x[u];
                acc[2][u] += sg0[e] * x[u];
                acc[3][u] += sa1[e] * x[u];
                acc[4][u] += sb1[e] * x[u];
                acc[5][u] += sg1[e] * x[u];
            }
        }
    }
    __hip_bfloat16* dsts[6] = { a00, b00, g10, a01, b01, g11 };
    const size_t base = (size_t)i * NPAD + j0;
    #pragma unroll
    for (int m = 0; m < 6; ++m) {
        __align__(8) __hip_bfloat16 h[4];
        #pragma unroll
        for (int u = 0; u < 4; ++u) h[u] = __float2bfloat16(acc[m][u]);
        *reinterpret_cast<uint2*>(&dsts[m][base]) = *reinterpret_cast<const uint2*>(h);
    }
}

// ---------------------------------------------------------------- row sums of the 4 (b0,g1) matrices
__global__ __launch_bounds__(256) void rowsum4(
    const __hip_bfloat16* __restrict__ M0, const __hip_bfloat16* __restrict__ M1,
    const __hip_bfloat16* __restrict__ M2, const __hip_bfloat16* __restrict__ M3,
    float* __restrict__ r1v)
{
    const __hip_bfloat16* M = (blockIdx.y == 0) ? M0 : (blockIdx.y == 1) ? M1
                            : (blockIdx.y == 2) ? M2 : M3;
    const size_t i = blockIdx.x;
    const int t = threadIdx.x;
    const __hip_bfloat16* row = M + i * NPAD;
    float s = 0.f;
    for (int k = t * 8; k < NPAD; k += 2048) {
        uint4 u = *reinterpret_cast<const uint4*>(&row[k]);
        const unsigned short* us = reinterpret_cast<const unsigned short*>(&u);
        #pragma unroll
        for (int e = 0; e < 8; ++e)
            s += __uint_as_float(((unsigned int)us[e]) << 16);
    }
    #pragma unroll
    for (int off = 32; off > 0; off >>= 1) s += __shfl_down(s, off);
    __shared__ float red[4];
    if ((t & 63) == 0) red[t >> 6] = s;
    __syncthreads();
    if (t == 0)
        r1v[(size_t)blockIdx.y * NPAD + i] = red[0] + red[1] + red[2] + red[3];
}

// ---------------------------------------------------------------- batched degree matvecs
// stage A (grid (NPAD,4)): y=0/1: dinv_c = 1/(a0_c . r1b_c + 1); y=2/3: mv1_c = b0_c . r1g_c
__global__ __launch_bounds__(256) void matvec_degA(
    const __hip_bfloat16* __restrict__ a0_0, const __hip_bfloat16* __restrict__ a0_1,
    const __hip_bfloat16* __restrict__ b0_0, const __hip_bfloat16* __restrict__ b0_1,
    const float* __restrict__ r1v,     // [4][NPAD]: b0c0,g1c0,b0c1,g1c1
    float* __restrict__ dinv2, float* __restrict__ mv12)
{
    const int y = blockIdx.y;
    const __hip_bfloat16* M = (y == 0) ? a0_0 : (y == 1) ? a0_1 : (y == 2) ? b0_0 : b0_1;
    const float* v = (y == 0) ? r1v : (y == 1) ? r1v + 2 * NPAD
                   : (y == 2) ? r1v + NPAD : r1v + 3 * NPAD;
    const size_t i = blockIdx.x;
    const int t = threadIdx.x;
    const __hip_bfloat16* row = M + i * NPAD;
    float s = 0.f;
    for (int k = t * 8; k < NPAD; k += 2048) {
        uint4 u = *reinterpret_cast<const uint4*>(&row[k]);
        const unsigned short* us = reinterpret_cast<const unsigned short*>(&u);
        #pragma unroll
        for (int e = 0; e < 8; ++e)
            s += __uint_as_float(((unsigned int)us[e]) << 16) * v[k + e];
    }
    #pragma unroll
    for (int off = 32; off > 0; off >>= 1) s += __shfl_down(s, off);
    __shared__ float red[4];
    if ((t & 63) == 0) red[t >> 6] = s;
    __syncthreads();
    if (t == 0) {
        float tot = red[0] + red[1] + red[2] + red[3];
        if (y < 2) dinv2[(size_t)y * NPAD + i] = 1.f / (tot + 1.f);
        else       mv12[(size_t)(y - 2) * NPAD + i] = tot;
    }
}

// stage B (grid (NPAD,2)): rsv_c = rsqrt(dinv_c*(a0_c . mv1_c + r1g_c) + 2)
__global__ __launch_bounds__(256) void matvec_degB(
    const __hip_bfloat16* __restrict__ a0_0, const __hip_bfloat16* __restrict__ a0_1,
    const float* __restrict__ mv12, const float* __restrict__ dinv2,
    const float* __restrict__ r1v, float* __restrict__ rsv2)
{
    const int c = blockIdx.y;
    const __hip_bfloat16* M = c ? a0_1 : a0_0;
    const float* v = mv12 + (size_t)c * NPAD;
    const float* add = r1v + (size_t)(2 * c + 1) * NPAD;
    const size_t i = blockIdx.x;
    const int t = threadIdx.x;
    const __hip_bfloat16* row = M + i * NPAD;
    float s = 0.f;
    for (int k = t * 8; k < NPAD; k += 2048) {
        uint4 u = *reinterpret_cast<const uint4*>(&row[k]);
        const unsigned short* us = reinterpret_cast<const unsigned short*>(&u);
        #pragma unroll
        for (int e = 0; e < 8; ++e)
            s += __uint_as_float(((unsigned int)us[e]) << 16) * v[k + e];
    }
    #pragma unroll
    for (int off = 32; off > 0; off >>= 1) s += __shfl_down(s, off);
    __shared__ float red[4];
    if ((t & 63) == 0) red[t >> 6] = s;
    __syncthreads();
    if (t == 0) {
        float tot = red[0] + red[1] + red[2] + red[3];
        rsv2[(size_t)c * NPAD + i] =
            rsqrtf(dinv2[(size_t)c * NPAD + i] * (tot + add[i]) + 2.f);
    }
}

// ---------------------------------------------------------------- DTI degree + scale (f32)
__global__ __launch_bounds__(256) void rowdeg_f32(
    const float* __restrict__ src, float* __restrict__ outv)
{
    const int i = blockIdx.x, t = threadIdx.x;
    float s = 0.f;
    if (i < NVALID) {
        const float* row = src + (size_t)i * 3000;
        for (int j4 = t; j4 < 750; j4 += 256) {
            float4 v = *reinterpret_cast<const float4*>(row + j4 * 4);
            s += v.x + v.y + v.z + v.w;
        }
    }
    #pragma unroll
    for (int off = 32; off > 0; off >>= 1) s += __shfl_down(s, off);
    __shared__ float red[4];
    if ((t & 63) == 0) red[t >> 6] = s;
    __syncthreads();
    if (t == 0) {
        float tot = red[0] + red[1] + red[2] + red[3];
        outv[i] = rsqrtf(tot + 2.f);
    }
}

__global__ __launch_bounds__(256) void scale_cast_f32(
    const float* __restrict__ src, int lds_, int nvalid,
    const float* __restrict__ vec, __hip_bfloat16* __restrict__ dst)
{
    const int i = blockIdx.y;
    const int j0 = (blockIdx.x * 256 + threadIdx.x) * 4;
    const float vi = vec[i];
    float v[4];
    if (i < nvalid && j0 + 3 < nvalid) {
        float4 f = *reinterpret_cast<const float4*>(src + (size_t)i * lds_ + j0);
        v[0] = f.x; v[1] = f.y; v[2] = f.z; v[3] = f.w;
    } else {
        #pragma unroll
        for (int u = 0; u < 4; ++u) {
            int j = j0 + u;
            v[u] = (i < nvalid && j < nvalid) ? src[(size_t)i * lds_ + j] : 0.f;
        }
    }
    #pragma unroll
    for (int u = 0; u < 4; ++u) {
        int j = j0 + u;
        if (j == i && i < nvalid) v[u] += 2.f;
        v[u] *= vi * vec[j];
    }
    __align__(8) __hip_bfloat16 h[4];
    #pragma unroll
    for (int u = 0; u < 4; ++u) h[u] = __float2bfloat16(v[u]);
    *reinterpret_cast<uint2*>(&dst[(size_t)i * NPAD + j0]) =
        *reinterpret_cast<const uint2*>(h);
}

// ---------------------------------------------------------------- transpose feature (f32 -> bf16^T)
__global__ __launch_bounds__(256) void transpose_feat(
    const float* __restrict__ X, int nvalid, __hip_bfloat16* __restrict__ XT)
{
    __shared__ float Ts[32][33];
    const int k0 = blockIdx.x * 32, n0 = blockIdx.y * 32;
    const int t = threadIdx.x, tr = t >> 5, tc = t & 31;
    #pragma unroll
    for (int p = 0; p < 4; ++p) {
        int k = k0 + tr + p * 8;
        Ts[tr + p * 8][tc] = (k < nvalid) ? X[(size_t)k * 128 + n0 + tc] : 0.f;
    }
    __syncthreads();
    #pragma unroll
    for (int p = 0; p < 4; ++p) {
        int n = tr + p * 8;
        XT[(size_t)(n0 + n) * NPAD + k0 + tc] = __float2bfloat16(Ts[tc][n]);
    }
}

// ---------------------------------------------------------------- scale columns of XT by rsv_c -> W0T_c (both channels)
__global__ __launch_bounds__(256) void scale_colsT2(
    const __hip_bfloat16* __restrict__ XT, const float* __restrict__ rsv2,
    __hip_bfloat16* __restrict__ W0T_0, __hip_bfloat16* __restrict__ W0T_1)
{
    const int c = blockIdx.z;
    const float* s = rsv2 + (size_t)c * NPAD;
    __hip_bfloat16* W0T = c ? W0T_1 : W0T_0;
    const int f = blockIdx.y;
    const int k0 = (blockIdx.x * 256 + threadIdx.x) * 8;
    if (k0 >= NPAD) return;
    uint4 u = *reinterpret_cast<const uint4*>(&XT[(size_t)f * NPAD + k0]);
    const unsigned short* us = reinterpret_cast<const unsigned short*>(&u);
    __align__(16) __hip_bfloat16 h[8];
    #pragma unroll
    for (int e = 0; e < 8; ++e) {
        float x = __uint_as_float(((unsigned int)us[e]) << 16);
        h[e] = __float2bfloat16(x * s[k0 + e]);
    }
    *reinterpret_cast<uint4*>(&W0T[(size_t)f * NPAD + k0]) =
        *reinterpret_cast<const uint4*>(h);
}

// ---------------------------------------------------------------- batched thin GEMM (up to 3 A/B pairs)
// grid (1, 24, NB*ZSPLIT); b = z/ZSPLIT selects pair; writes f32 partials at slot b.
__global__ __launch_bounds__(256, 3) void gemm_bt_batch(
    const __hip_bfloat16* __restrict__ A0, const __hip_bfloat16* __restrict__ B0,
    const __hip_bfloat16* __restrict__ A1, const __hip_bfloat16* __restrict__ B1,
    const __hip_bfloat16* __restrict__ A2, const __hip_bfloat16* __restrict__ B2,
    float* __restrict__ part)
{
    const int b  = blockIdx.z / ZSPLIT;
    const int zz = blockIdx.z % ZSPLIT;
    const __hip_bfloat16* A  = (b == 0) ? A0 : (b == 1) ? A1 : A2;
    const __hip_bfloat16* BT = (b == 0) ? B0 : (b == 1) ? B1 : B2;
    float* C = part + (size_t)b * SLOT + (size_t)zz * PSTRIDE;

    __shared__ __align__(16) __hip_bfloat16 As[128 * 32];
    __shared__ __align__(16) __hip_bfloat16 Bs[128 * 32];
    const int t = threadIdx.x;
    const int lane = t & 63;
    const int w = t >> 6;
    const int wm = w >> 1, wn = w & 1;
    const int tm = blockIdx.y;
    const int kbeg = zz * KCHUNK;

    const int srow = lane >> 2;
    const int skg  = (lane & 3) * 8;
    const __hip_bfloat16* Ag = A  + (size_t)(tm * 128 + w * 32 + srow) * NPAD + skg;
    const __hip_bfloat16* Bg = BT + (size_t)(w * 32 + srow) * NPAD + skg;
    __hip_bfloat16* Al0 = &As[w * 1024];
    __hip_bfloat16* Al1 = &As[w * 1024 + 512];
    __hip_bfloat16* Bl0 = &Bs[w * 1024];
    __hip_bfloat16* Bl1 = &Bs[w * 1024 + 512];

    floatx4 acc[4][4] = {};

    for (int k0 = kbeg; k0 < kbeg + KCHUNK; k0 += 32) {
        __syncthreads();
        gload16(Ag + k0,             Al0);
        gload16(Ag + 16 * NPAD + k0, Al1);
        gload16(Bg + k0,             Bl0);
        gload16(Bg + 16 * NPAD + k0, Bl1);
        __syncthreads();

        bf16x8 af[4], bfv[4];
        const int koff = (lane >> 4) * 8;
        #pragma unroll
        for (int mi = 0; mi < 4; ++mi)
            af[mi] = *reinterpret_cast<const bf16x8*>(
                &As[(wm * 64 + mi * 16 + (lane & 15)) * 32 + koff]);
        #pragma unroll
        for (int ni = 0; ni < 4; ++ni)
            bfv[ni] = *reinterpret_cast<const bf16x8*>(
                &Bs[(wn * 64 + ni * 16 + (lane & 15)) * 32 + koff]);
        #pragma unroll
        for (int mi = 0; mi < 4; ++mi)
            #pragma unroll
            for (int ni = 0; ni < 4; ++ni)
                acc[mi][ni] = __builtin_amdgcn_mfma_f32_16x16x32_bf16(
                    af[mi], bfv[ni], acc[mi][ni], 0, 0, 0);
    }

    const int r0 = tm * 128 + wm * 64 + ((lane >> 4) << 2);
    const int c0 = wn * 64 + (lane & 15);
    #pragma unroll
    for (int mi = 0; mi < 4; ++mi)
        #pragma unroll
        for (int ni = 0; ni < 4; ++ni)
            #pragma unroll
            for (int r = 0; r < 4; ++r)
                C[(size_t)(r0 + mi * 16 + r) * 128 + c0 + ni * 16] = acc[mi][ni][r];
}

// ---------------------------------------------------------------- final GEMM (sigmoid epilogue)
__global__ __launch_bounds__(256, 3) void gemm_sig(
    const __hip_bfloat16* __restrict__ A, const __hip_bfloat16* __restrict__ BT,
    float* __restrict__ C, int Kchunk, int lda, int ldb, int ldc,
    int Mvalid, int Nvalid)
{
    __shared__ __align__(16) __hip_bfloat16 As[128 * 32];
    __shared__ __align__(16) __hip_bfloat16 Bs[128 * 32];
    const int t = threadIdx.x;
    const int lane = t & 63;
    const int w = t >> 6;
    const int wm = w >> 1, wn = w & 1;
    const int tm = blockIdx.y, tn = blockIdx.x;

    const int srow = lane >> 2;
    const int skg  = (lane & 3) * 8;
    const __hip_bfloat16* Ag = A  + (size_t)(tm * 128 + w * 32 + srow) * lda + skg;
    const __hip_bfloat16* Bg = BT + (size_t)(tn * 128 + w * 32 + srow) * ldb + skg;
    __hip_bfloat16* Al0 = &As[w * 1024];
    __hip_bfloat16* Al1 = &As[w * 1024 + 512];
    __hip_bfloat16* Bl0 = &Bs[w * 1024];
    __hip_bfloat16* Bl1 = &Bs[w * 1024 + 512];

    floatx4 acc[4][4] = {};

    for (int k0 = 0; k0 < Kchunk; k0 += 32) {
        __syncthreads();
        gload16(Ag + k0,            Al0);
        gload16(Ag + 16 * lda + k0, Al1);
        gload16(Bg + k0,            Bl0);
        gload16(Bg + 16 * ldb + k0, Bl1);
        __syncthreads();

        bf16x8 af[4], bfv[4];
        const int koff = (lane >> 4) * 8;
        #pragma unroll
        for (int mi = 0; mi < 4; ++mi)
            af[mi] = *reinterpret_cast<const bf16x8*>(
                &As[(wm * 64 + mi * 16 + (lane & 15)) * 32 + koff]);
        #pragma unroll
        for (int ni = 0; ni < 4; ++ni)
            bfv[ni] = *reinterpret_cast<const bf16x8*>(
                &Bs[(wn * 64 + ni * 16 + (lane & 15)) * 32 + koff]);
        #pragma unroll
        for (int mi = 0; mi < 4; ++mi)
            #pragma unroll
            for (int ni = 0; ni < 4; ++ni)
                acc[mi][ni] = __builtin_amdgcn_mfma_f32_16x16x32_bf16(
                    af[mi], bfv[ni], acc[mi][ni], 0, 0, 0);
    }

    const int r0 = tm * 128 + wm * 64 + ((lane >> 4) << 2);
    const int c0 = tn * 128 + wn * 64 + (lane & 15);
    #pragma unroll
    for (int mi = 0; mi < 4; ++mi)
        #pragma unroll
        for (int ni = 0; ni < 4; ++ni) {
            const int col = c0 + ni * 16;
            #pragma unroll
            for (int r = 0; r < 4; ++r) {
                const int row = r0 + mi * 16 + r;
                if (row < Mvalid && col < Nvalid)
                    C[(size_t)row * ldc + col] =
                        1.f / (1.f + __expf(-acc[mi][ni][r]));
            }
        }
}

// ---------------------------------------------------------------- batched K-split reduce + transpose
// grid (96, 4, NB); b selects part slot + outputs. Rm output optional (nullptr).
__global__ __launch_bounds__(256) void reduce_trans_b(
    const float* __restrict__ part,
    __hip_bfloat16* __restrict__ X0, __hip_bfloat16* __restrict__ X1,
    __hip_bfloat16* __restrict__ X2,
    __hip_bfloat16* __restrict__ R0, __hip_bfloat16* __restrict__ R1,
    __hip_bfloat16* __restrict__ R2)
{
    const int b = blockIdx.z;
    const float* Pp = part + (size_t)b * SLOT;
    __hip_bfloat16* XT = (b == 0) ? X0 : (b == 1) ? X1 : X2;
    __hip_bfloat16* Rm = (b == 0) ? R0 : (b == 1) ? R1 : R2;

    __shared__ float Ts[32][33];
    const int k0 = blockIdx.x * 32, n0 = blockIdx.y * 32;
    const int t = threadIdx.x, tr = t >> 5, tc = t & 31;
    #pragma unroll
    for (int p = 0; p < 4; ++p) {
        int i = k0 + tr + p * 8;
        float s = 0.f;
        #pragma unroll
        for (int z = 0; z < ZSPLIT; ++z)
            s += Pp[(size_t)z * PSTRIDE + (size_t)i * 128 + n0 + tc];
        Ts[tr + p * 8][tc] = s;
        if (Rm) Rm[(size_t)i * 128 + n0 + tc] = __float2bfloat16(s);
    }
    __syncthreads();
    #pragma unroll
    for (int p = 0; p < 4; ++p) {
        int n = tr + p * 8;
        XT[(size_t)(n0 + n) * NPAD + k0 + tc] = __float2bfloat16(Ts[tc][n]);
    }
}

// ---------------------------------------------------------------- DTI hop2: reduce + attention write
__global__ __launch_bounds__(256) void reduce_att_f32(
    const float* __restrict__ Pp, const float* __restrict__ ap,
    float* __restrict__ conv)
{
    const int idx = blockIdx.x * 256 + threadIdx.x;
    float s = 0.f;
    #pragma unroll
    for (int z = 0; z < ZSPLIT; ++z)
        s += Pp[(size_t)z * PSTRIDE + idx];
    float a0 = ap[0], a1 = ap[1], a2 = ap[2];
    float m = fmaxf(a0, fmaxf(a1, a2));
    float e0 = __expf(a0 - m), e1 = __expf(a1 - m), e2 = __expf(a2 - m);
    conv[idx] = (e0 / (e0 + e1 + e2)) * s;
}

// ---------------------------------------------------------------- batched hop1 combine (grid (96,4,2))
__global__ __launch_bounds__(256) void combine_mid2(
    const float* __restrict__ part,
    const __hip_bfloat16* __restrict__ Zrm0, const __hip_bfloat16* __restrict__ Zrm1,
    const float* __restrict__ X,
    const float* __restrict__ rsv2, const float* __restrict__ dinv2,
    __hip_bfloat16* __restrict__ WpT0, __hip_bfloat16* __restrict__ WpT1,
    __hip_bfloat16* __restrict__ Wprm0, __hip_bfloat16* __restrict__ Wprm1)
{
    const int c = blockIdx.z;
    const float* Vp = part + (size_t)c * SLOT;
    const __hip_bfloat16* Zrm = c ? Zrm1 : Zrm0;
    const float* sv = rsv2 + (size_t)c * NPAD;
    const float* dv = dinv2 + (size_t)c * NPAD;
    __hip_bfloat16* WpT  = c ? WpT1 : WpT0;
    __hip_bfloat16* Wprm = c ? Wprm1 : Wprm0;

    __shared__ float Ts[32][33];
    const int k0 = blockIdx.x * 32, n0 = blockIdx.y * 32;
    const int t = threadIdx.x, tr = t >> 5, tc = t & 31;
    #pragma unroll
    for (int p = 0; p < 4; ++p) {
        int i = k0 + tr + p * 8;
        int f = n0 + tc;
        float vsum = b2f(Zrm[(size_t)i * 128 + f]);
        #pragma unroll
        for (int z = 0; z < ZSPLIT; ++z)
            vsum += Vp[(size_t)z * PSTRIDE + (size_t)i * 128 + f];
        float x  = (i < NVALID) ? X[(size_t)i * 128 + f] : 0.f;
        float si = sv[i];
        float out1 = si * dv[i] * vsum + 2.f * si * si * x;
        float wv = si * out1;
        Ts[tr + p * 8][tc] = wv;
        Wprm[(size_t)i * 128 + f] = __float2bfloat16(wv);
    }
    __syncthreads();
    #pragma unroll
    for (int p = 0; p < 4; ++p) {
        int n = tr + p * 8;
        WpT[(size_t)(n0 + n) * NPAD + k0 + tc] = __float2bfloat16(Ts[tc][n]);
    }
}

// ---------------------------------------------------------------- hop2 combine + attention for BOTH channels
__global__ __launch_bounds__(256) void combine_att2(
    const float* __restrict__ part,
    const __hip_bfloat16* __restrict__ Zrm0, const __hip_bfloat16* __restrict__ Zrm1,
    const __hip_bfloat16* __restrict__ Wprm0, const __hip_bfloat16* __restrict__ Wprm1,
    const float* __restrict__ rsv2, const float* __restrict__ dinv2,
    const float* __restrict__ ap, float* __restrict__ conv)
{
    const int idx = blockIdx.x * 256 + threadIdx.x;  // grid 1500 -> 3000*128
    const int i = idx >> 7;
    float v0 = b2f(Zrm0[idx]);
    float v1 = b2f(Zrm1[idx]);
    #pragma unroll
    for (int z = 0; z < ZSPLIT; ++z) {
        v0 += part[(size_t)z * PSTRIDE + idx];
        v1 += part[SLOT + (size_t)z * PSTRIDE + idx];
    }
    float s0 = rsv2[i],        d0 = dinv2[i];
    float s1 = rsv2[NPAD + i], d1 = dinv2[NPAD + i];
    float o0 = s0 * d0 * v0 + 2.f * s0 * b2f(Wprm0[idx]);
    float o1 = s1 * d1 * v1 + 2.f * s1 * b2f(Wprm1[idx]);
    float a0 = ap[0], a1 = ap[1], a2 = ap[2];
    float m = fmaxf(a0, fmaxf(a1, a2));
    float e0 = __expf(a0 - m), e1 = __expf(a1 - m), e2 = __expf(a2 - m);
    float inv = 1.f / (e0 + e1 + e2);
    conv[idx] += (e1 * inv) * o0 + (e2 * inv) * o1;
}

// ---------------------------------------------------------------- final split+cast
__global__ __launch_bounds__(256) void cast_split(
    const float* __restrict__ acc, __hip_bfloat16* __restrict__ dF,
    __hip_bfloat16* __restrict__ pF)
{
    const int idx = blockIdx.x * 256 + threadIdx.x;
    if (idx < 1024 * 128) {
        int r = idx >> 7;
        dF[idx] = __float2bfloat16(r < 1000 ? acc[idx] : 0.f);
    } else {
        int j = idx - 1024 * 128;
        int r = j >> 7;
        pF[j] = __float2bfloat16(r < 2000 ? acc[(size_t)(1000 + r) * 128 + (j & 127)] : 0.f);
    }
}

// ================================================================ launch
extern "C" void kernel_launch(void* const* d_in, const int* in_sizes, int n_in,
                              void* d_out, int out_size, void* d_ws, size_t ws_size,
                              hipStream_t stream)
{
    const float* A     = (const float*)d_in[0];
    const float* DTI   = (const float*)d_in[1];
    const float* drugS = (const float*)d_in[2];
    const float* protS = (const float*)d_in[3];
    const float* w0a   = (const float*)d_in[4];
    const float* w0b   = (const float*)d_in[5];
    const float* w1g   = (const float*)d_in[6];
    const float* ap    = (const float*)d_in[7];
    const float* wd1 = (const float*)d_in[10]; const float* bd1 = (const float*)d_in[11];
    const float* wd2 = (const float*)d_in[12]; const float* bd2 = (const float*)d_in[13];
    const float* wd3 = (const float*)d_in[14]; const float* bd3 = (const float*)d_in[15];
    const float* wp1 = (const float*)d_in[16]; const float* bp1 = (const float*)d_in[17];
    const float* wp2 = (const float*)d_in[18]; const float* bp2 = (const float*)d_in[19];
    const float* wp3 = (const float*)d_in[20]; const float* bp3 = (const float*)d_in[21];
    float* out = (float*)d_out;

    const size_t SQ_BF  = (size_t)NPAD * NPAD * 2;
    const size_t PAN_BF = (size_t)128 * NPAD * 2;
    char* p = (char*)d_ws;
    auto alloc = [&](size_t sz) { char* r = p; p += (sz + 255) & ~(size_t)255; return r; };
    __hip_bfloat16* sdti = (__hip_bfloat16*)alloc(SQ_BF);
    __hip_bfloat16* a0c[2], *b0c[2], *g1c[2];
    for (int c = 0; c < 2; ++c) {
        a0c[c] = (__hip_bfloat16*)alloc(SQ_BF);
        b0c[c] = (__hip_bfloat16*)alloc(SQ_BF);
        g1c[c] = (__hip_bfloat16*)alloc(SQ_BF);
    }
    float* part  = (float*)alloc((size_t)3 * SLOT * 4);      // 3 slots f32 partials (37.7 MB)
    float* r1v   = (float*)alloc((size_t)4 * NPAD * 4);
    float* dinv2 = (float*)alloc((size_t)2 * NPAD * 4);
    float* mv12  = (float*)alloc((size_t)2 * NPAD * 4);
    float* rsv2  = (float*)alloc((size_t)2 * NPAD * 4);
    float* degv  = (float*)alloc((size_t)NPAD * 4);
    float* fb    = (float*)alloc((size_t)NPAD * 128 * 4);
    float* conv  = (float*)alloc((size_t)NPAD * 128 * 4);
    __hip_bfloat16* XTF  = (__hip_bfloat16*)alloc(PAN_BF);
    __hip_bfloat16* XT2  = (__hip_bfloat16*)alloc(PAN_BF);
    __hip_bfloat16* W0T_0 = (__hip_bfloat16*)alloc(PAN_BF);
    __hip_bfloat16* W0T_1 = (__hip_bfloat16*)alloc(PAN_BF);
    __hip_bfloat16* ZT_0  = (__hip_bfloat16*)alloc(PAN_BF);
    __hip_bfloat16* ZT_1  = (__hip_bfloat16*)alloc(PAN_BF);
    __hip_bfloat16* Zrm_0 = (__hip_bfloat16*)alloc(PAN_BF);
    __hip_bfloat16* Zrm_1 = (__hip_bfloat16*)alloc(PAN_BF);
    __hip_bfloat16* UT_0  = (__hip_bfloat16*)alloc(PAN_BF);
    __hip_bfloat16* UT_1  = (__hip_bfloat16*)alloc(PAN_BF);
    __hip_bfloat16* WpT_0 = (__hip_bfloat16*)alloc(PAN_BF);
    __hip_bfloat16* WpT_1 = (__hip_bfloat16*)alloc(PAN_BF);
    __hip_bfloat16* Wprm_0 = (__hip_bfloat16*)alloc(PAN_BF);
    __hip_bfloat16* Wprm_1 = (__hip_bfloat16*)alloc(PAN_BF);
    __hip_bfloat16* dF = (__hip_bfloat16*)alloc((size_t)1024 * 128 * 2);
    __hip_bfloat16* pF = (__hip_bfloat16*)alloc((size_t)2048 * 128 * 2);
    if ((size_t)(p - (char*)d_ws) > ws_size) return;  // fail loud if ws too small

    // ---- fused MLPs -> fb; transpose
    mlp_fused<<<375, 256, 0, stream>>>(drugS, protS,
        wd1, bd1, wd2, bd2, wd3, bd3, wp1, bp1, wp2, bp2, wp3, bp3, fb);
    transpose_feat<<<dim3(96, 4), 256, 0, stream>>>(fb, 3000, XTF);

    // ---- gtconv + rowsums
    gtconv_stream<<<dim3(3, NPAD), 256, 0, stream>>>(A, w0a, w0b, w1g,
        a0c[0], b0c[0], g1c[0], a0c[1], b0c[1], g1c[1]);
    rowsum4<<<dim3(NPAD, 4), 256, 0, stream>>>(b0c[0], g1c[0], b0c[1], g1c[1], r1v);

    // ---- DTI normalize
    rowdeg_f32<<<NPAD, 256, 0, stream>>>(DTI, degv);
    scale_cast_f32<<<dim3(3, NPAD), 256, 0, stream>>>(DTI, 3000, 3000, degv, sdti);

    // ---- batched degree matvecs + W0T
    matvec_degA<<<dim3(NPAD, 4), 256, 0, stream>>>(a0c[0], a0c[1], b0c[0], b0c[1],
        r1v, dinv2, mv12);
    matvec_degB<<<dim3(NPAD, 2), 256, 0, stream>>>(a0c[0], a0c[1], mv12, dinv2, r1v, rsv2);
    scale_colsT2<<<dim3(2, 128, 2), 256, 0, stream>>>(XTF, rsv2, W0T_0, W0T_1);

    // ---- S1: {sdti@XTF, g1_0@W0T_0, g1_1@W0T_1}
    gemm_bt_batch<<<dim3(1, 24, 24), 256, 0, stream>>>(
        sdti, XTF, g1c[0], W0T_0, g1c[1], W0T_1, part);
    reduce_trans_b<<<dim3(96, 4, 3), 256, 0, stream>>>(part,
        XT2, ZT_0, ZT_1, nullptr, Zrm_0, Zrm_1);

    // ---- S2: {sdti@XT2, b0_0@ZT_0, b0_1@ZT_1}
    gemm_bt_batch<<<dim3(1, 24, 24), 256, 0, stream>>>(
        sdti, XT2, b0c[0], ZT_0, b0c[1], ZT_1, part);
    reduce_att_f32<<<1500, 256, 0, stream>>>(part, ap, conv);          // DTI done (slot 0)
    reduce_trans_b<<<dim3(96, 4, 2), 256, 0, stream>>>(part + SLOT,
        UT_0, UT_1, nullptr, nullptr, nullptr, nullptr);

    // ---- S3: {a0_0@UT_0, a0_1@UT_1} ; hop1 combine
    gemm_bt_batch<<<dim3(1, 24, 16), 256, 0, stream>>>(
        a0c[0], UT_0, a0c[1], UT_1, nullptr, nullptr, part);
    combine_mid2<<<dim3(96, 4, 2), 256, 0, stream>>>(part, Zrm_0, Zrm_1, fb,
        rsv2, dinv2, WpT_0, WpT_1, Wprm_0, Wprm_1);

    // ---- S4..S6: hop2
    gemm_bt_batch<<<dim3(1, 24, 16), 256, 0, stream>>>(
        g1c[0], WpT_0, g1c[1], WpT_1, nullptr, nullptr, part);
    reduce_trans_b<<<dim3(96, 4, 2), 256, 0, stream>>>(part,
        ZT_0, ZT_1, nullptr, Zrm_0, Zrm_1, nullptr);
    gemm_bt_batch<<<dim3(1, 24, 16), 256, 0, stream>>>(
        b0c[0], ZT_0, b0c[1], ZT_1, nullptr, nullptr, part);
    reduce_trans_b<<<dim3(96, 4, 2), 256, 0, stream>>>(part,
        UT_0, UT_1, nullptr, nullptr, nullptr, nullptr);
    gemm_bt_batch<<<dim3(1, 24, 16), 256, 0, stream>>>(
        a0c[0], UT_0, a0c[1], UT_1, nullptr, nullptr, part);
    combine_att2<<<1500, 256, 0, stream>>>(part, Zrm_0, Zrm_1, Wprm_0, Wprm_1,
        rsv2, dinv2, ap, conv);

    // ---- final: sigmoid(drug @ prot^T)
    cast_split<<<1536, 256, 0, stream>>>(conv, dF, pF);
    gemm_sig<<<dim3(16, 8), 256, 0, stream>>>(dF, pF, out, 128, 128, 128, 2000, 1000, 2000);
}